// Round 8
// baseline (567.761 us; speedup 1.0000x reference)
//
#include <hip/hip_runtime.h>
#include <math.h>

// MTGCN R6: atomic-free CSR build via LDS histograms + rank trick.
//  - hist_rank: 64 blocks x 12.5K-edge chunks, 8 phases ({src,dst} x 4 key ranges,
//    12800 bins x u32 = 51KB LDS); dst phases record per-edge rank (LDS atomic ret).
//  - reduce_hist: partials -> dinv + cnt (no global atomics anywhere).
//  - fill_csr2: pos = ptr[d] + base16[b][d] + rank[e]; writes packed int2{src,wbits}.
// Rest as R5b: bf16 MFMA GEMMs, fp8 128B-line rows for gathers/loss, eighth-wave.

typedef unsigned short ushort_t;
typedef unsigned char u8;
typedef __attribute__((ext_vector_type(8))) __bf16 bf16x8;
typedef __attribute__((ext_vector_type(8))) short s16x8;
typedef __attribute__((ext_vector_type(4))) float f32x4;
typedef __attribute__((ext_vector_type(2))) float f32x2;

#define NB_H 64      // histogram blocks (chunks)
#define NR 4         // key ranges
#define RK 12800     // bins per range (4*12800 >= 50000)

__device__ __forceinline__ f32x4 mfma16x16x32(s16x8 a, s16x8 b, f32x4 c) {
  return __builtin_amdgcn_mfma_f32_16x16x32_bf16(
      __builtin_bit_cast(bf16x8, a), __builtin_bit_cast(bf16x8, b), c, 0, 0, 0);
}
__device__ __forceinline__ ushort_t f2bf(float f) {
  union { float f; unsigned u; } c; c.f = f;
  unsigned r = (c.u + 0x7FFFu + ((c.u >> 16) & 1u)) >> 16;
  return (ushort_t)r;
}
__device__ __forceinline__ f32x2 cvt2lo(unsigned u) {
  return __builtin_amdgcn_cvt_pk_f32_fp8((int)u, false);
}
__device__ __forceinline__ f32x2 cvt2hi(unsigned u) {
  return __builtin_amdgcn_cvt_pk_f32_fp8((int)u, true);
}
__device__ __forceinline__ u8 f2fp8(float f) {
  return (u8)(__builtin_amdgcn_cvt_pk_fp8_f32(f, 0.f, 0, false) & 0xff);
}

// =======================================================================
// MFMA GEMM (unchanged from R5b)
// =======================================================================
template<int VAR, int NT, int KTOT>
__global__ __launch_bounds__(256) void gemm_mfma(
    const ushort_t* __restrict__ A0, const ushort_t* __restrict__ A1,
    const ushort_t* __restrict__ Wt,
    const float* __restrict__ bias0, const float* __restrict__ bias1,
    const float* __restrict__ x1,
    const float* __restrict__ W3c, const float* __restrict__ b3c,
    void* __restrict__ out0, void* __restrict__ out1,
    float* __restrict__ t0g, float* __restrict__ t1g, int M)
{
  constexpr int NF = NT / 32;
  __shared__ __align__(16) ushort_t As[64 * 40];
  __shared__ __align__(16) ushort_t Bs[NT * 40];
  __shared__ float w3s[400];
  const int tid  = threadIdx.x;
  const int lane = tid & 63, w = tid >> 6;
  const int m0 = blockIdx.x * 64;
  const int wm = (w & 1) * 32, wn = (w >> 1) * (NT / 2);
  if (VAR == 2) { for (int i = tid; i < 400; i += 256) w3s[i] = W3c[i]; }
  f32x4 acc[2][NF];
#pragma unroll
  for (int i = 0; i < 2; ++i)
#pragma unroll
    for (int j = 0; j < NF; ++j) acc[i][j] = (f32x4){0.f, 0.f, 0.f, 0.f};

  for (int k0 = 0; k0 < KTOT; k0 += 32) {
    { // A stage
      const int r = tid >> 2, c8 = (tid & 3) * 8;
      const int gm = m0 + r;
      uint4 v = {0u, 0u, 0u, 0u};
      if (gm < M) {
        const ushort_t* srcp;
        if (VAR == 0) srcp = (k0 < 128) ? A0 + (size_t)gm * 128 + k0 + c8
                                        : A1 + (size_t)gm * 128 + (k0 - 128) + c8;
        else if (VAR == 1) srcp = A0 + (size_t)gm * 320 + k0 + c8;
        else srcp = A0 + (size_t)gm * 128 + k0 + c8;
        v = *(const uint4*)srcp;
      }
      *(uint4*)&As[r * 40 + c8] = v;
    }
    { // B stage
      const int c8 = (tid & 3) * 8;
#pragma unroll
      for (int i = 0; i < (NT * 4 + 255) / 256; ++i) {
        const int r = (tid >> 2) + i * 64;
        if (r < NT)
          *(uint4*)&Bs[r * 40 + c8] = *(const uint4*)(Wt + (size_t)r * KTOT + k0 + c8);
      }
    }
    __syncthreads();
    s16x8 af[2], bfr[NF];
#pragma unroll
    for (int mi = 0; mi < 2; ++mi)
      af[mi] = *(const s16x8*)&As[(wm + mi * 16 + (lane & 15)) * 40 + (lane >> 4) * 8];
#pragma unroll
    for (int ni = 0; ni < NF; ++ni)
      bfr[ni] = *(const s16x8*)&Bs[(wn + ni * 16 + (lane & 15)) * 40 + (lane >> 4) * 8];
#pragma unroll
    for (int mi = 0; mi < 2; ++mi)
#pragma unroll
      for (int ni = 0; ni < NF; ++ni)
        acc[mi][ni] = mfma16x16x32(af[mi], bfr[ni], acc[mi][ni]);
    __syncthreads();
  }

  if (VAR == 2) {
#pragma unroll
    for (int mi = 0; mi < 2; ++mi)
#pragma unroll
      for (int r = 0; r < 4; ++r) {
        const int gRow = m0 + wm + mi * 16 + ((lane >> 4) << 2) + r;
        float p0 = 0.f, p1 = 0.f, p2 = 0.f, p3 = 0.f;
#pragma unroll
        for (int ni = 0; ni < NF; ++ni) {
          const int col = wn + ni * 16 + (lane & 15);
          const float v = acc[mi][ni][r];
          if (gRow < M) {
            if (col < 100) {
              const float x2v = x1[(size_t)gRow * 128 + col] + fmaxf(v + bias0[col], 0.f);
              p0 = fmaf(x2v, w3s[col * 2 + 0], p0);
              p1 = fmaf(x2v, w3s[col * 2 + 1], p1);
              p2 = fmaf(x2v, w3s[200 + col * 2 + 0], p2);
              p3 = fmaf(x2v, w3s[200 + col * 2 + 1], p3);
            } else if (col < 200) {
              const int c = col - 100;
              ((u8*)out1)[(size_t)gRow * 128 + c] =
                  f2fp8(x1[(size_t)gRow * 128 + c] + fmaxf(v + bias1[c], 0.f));
            }
          }
        }
        if (wn == 0) {
#pragma unroll
          for (int off = 8; off; off >>= 1) {
            p0 += __shfl_down(p0, off, 16);
            p1 += __shfl_down(p1, off, 16);
            p2 += __shfl_down(p2, off, 16);
            p3 += __shfl_down(p3, off, 16);
          }
          if ((lane & 15) == 0 && gRow < M) {
            t0g[(size_t)gRow * 2 + 0] = p0 + b3c[0];
            t0g[(size_t)gRow * 2 + 1] = p1 + b3c[1];
            t1g[(size_t)gRow * 2 + 0] = p2;
            t1g[(size_t)gRow * 2 + 1] = p3;
          }
        }
      }
  } else {
#pragma unroll
    for (int mi = 0; mi < 2; ++mi)
#pragma unroll
      for (int ni = 0; ni < NF; ++ni)
#pragma unroll
        for (int r = 0; r < 4; ++r) {
          const int gRow = m0 + wm + mi * 16 + ((lane >> 4) << 2) + r;
          const int col  = wn + ni * 16 + (lane & 15);
          if (gRow >= M) continue;
          const float v = acc[mi][ni][r];
          if (VAR == 0) {
            ushort_t* h = (ushort_t*)out0;
            h[(size_t)gRow * 320 + col] = (col < 300) ? f2bf(fmaxf(v + bias0[col], 0.f))
                                                      : (ushort_t)0;
          } else {
            if (col < 100) ((float*)out0)[(size_t)gRow * 128 + col] = v + bias0[col];
            else if (col < 200) ((u8*)out1)[(size_t)gRow * 128 + (col - 100)] = f2fp8(v);
          }
        }
  }
}

// ---------------- packing / conversion ----------------
__global__ void cvt_x_kernel(const float* __restrict__ x, ushort_t* __restrict__ xb,
                             u8* __restrict__ xf8, int n4) {
  const int i = blockIdx.x * 256 + threadIdx.x;
  if (i < n4) {
    const float4 v = ((const float4*)x)[i];
    ushort4 o; o.x = f2bf(v.x); o.y = f2bf(v.y); o.z = f2bf(v.z); o.w = f2bf(v.w);
    ((ushort4*)xb)[i] = o;
    int p = 0;
    p = __builtin_amdgcn_cvt_pk_fp8_f32(v.x, v.y, p, false);
    p = __builtin_amdgcn_cvt_pk_fp8_f32(v.z, v.w, p, true);
    ((unsigned*)xf8)[i] = (unsigned)p;
  }
}
__global__ void pack_all(const float* __restrict__ W1, const float* __restrict__ W2,
                         const float* __restrict__ l1W, const float* __restrict__ l2W,
                         ushort_t* __restrict__ W1t, ushort_t* __restrict__ W2t,
                         ushort_t* __restrict__ Wlt) {
  const int i = blockIdx.x * 256 + threadIdx.x;
  if (i < 81920) {                       // W1t [320][256]
    const int n = i >> 8, k = i & 255;
    float v = 0.f;
    if (n < 300) v = (k < 128) ? W1[k * 300 + n] : W1[38400 + (k - 128) * 300 + n];
    W1t[i] = f2bf(v);
  } else if (i < 153600) {               // W2t [224][320]
    const int j = i - 81920;
    const int n = j / 320, k = j - n * 320;
    float v = 0.f;
    if (n < 200 && k < 300) v = W2[(n < 100 ? 0 : 30000) + k * 100 + (n % 100)];
    W2t[j] = f2bf(v);
  } else if (i < 182272) {               // Wlt [224][128]
    const int j = i - 153600;
    const int n = j >> 7, k = j & 127;
    float v = 0.f;
    if (n < 100) v = l1W[n * 128 + k];
    else if (n < 200) v = l2W[(n - 100) * 128 + k];
    Wlt[j] = f2bf(v);
  }
}

// ---------------- histogram + rank (no global atomics) ----------------
__global__ __launch_bounds__(256) void hist_rank(
    const int* __restrict__ src, const int* __restrict__ dst, int E, int M,
    ushort_t* __restrict__ partS, ushort_t* __restrict__ partD,
    ushort_t* __restrict__ rank)
{
  __shared__ unsigned hist[RK];
  const int b = blockIdx.x;
  const int cs = (E + NB_H - 1) / NB_H;
  const int e0 = b * cs;
  const int e1 = (e0 + cs < E) ? e0 + cs : E;
  for (int isD = 0; isD < 2; ++isD) {
    const int* keys = isD ? dst : src;
    ushort_t* part = isD ? partD : partS;
    for (int r = 0; r < NR; ++r) {
      const int klo = r * RK;
      for (int i = threadIdx.x; i < RK; i += 256) hist[i] = 0;
      __syncthreads();
      for (int e = e0 + threadIdx.x; e < e1; e += 256) {
        const int k = keys[e] - klo;
        if ((unsigned)k < (unsigned)RK) {
          const unsigned old = atomicAdd(&hist[k], 1u);
          if (isD) rank[e] = (ushort_t)old;
        }
      }
      __syncthreads();
      for (int i = threadIdx.x; i < RK; i += 256) {
        const int k = klo + i;
        if (k < M) part[(size_t)b * M + k] = (ushort_t)hist[i];
      }
      __syncthreads();
    }
  }
}

// partials -> dinv (1/sqrt(out-deg)) and cnt (in-deg)
__global__ void reduce_hist(const ushort_t* __restrict__ partS,
                            const ushort_t* __restrict__ partD,
                            float* __restrict__ dinv, int* __restrict__ cnt, int M)
{
  const int k = blockIdx.x * 256 + threadIdx.x;
  if (k >= M) return;
  unsigned s = 0, d = 0;
  for (int b = 0; b < NB_H; ++b) {
    s += partS[(size_t)b * M + k];
    d += partD[(size_t)b * M + k];
  }
  dinv[k] = (s > 0) ? 1.f / sqrtf((float)s) : 0.f;
  cnt[k] = (int)d;
}

// per-bin exclusive prefix over blocks (relative to ptr[k]) -> u16 table
__global__ void base_tab(const ushort_t* __restrict__ partD,
                         ushort_t* __restrict__ base16, int M)
{
  const int k = blockIdx.x * 256 + threadIdx.x;
  if (k >= M) return;
  unsigned run = 0;
  for (int b = 0; b < NB_H; ++b) {
    base16[(size_t)b * M + k] = (ushort_t)run;
    run += partD[(size_t)b * M + k];
  }
}

// ---------------- CSR build: scan (unchanged) + atomic-free fill
__global__ void scan_local(const int* __restrict__ cnt, int* __restrict__ ptr,
                           int* __restrict__ bsum, int n)
{
  __shared__ int tmp[256];
  const int i = blockIdx.x * 256 + threadIdx.x;
  const int v = (i < n) ? cnt[i] : 0;
  tmp[threadIdx.x] = v;
  __syncthreads();
  for (int off = 1; off < 256; off <<= 1) {
    const int t = (threadIdx.x >= off) ? tmp[threadIdx.x - off] : 0;
    __syncthreads();
    tmp[threadIdx.x] += t;
    __syncthreads();
  }
  if (i < n) ptr[i] = tmp[threadIdx.x] - v;
  if (threadIdx.x == 255) bsum[blockIdx.x] = tmp[255];
}
__global__ void scan_bsum(int* __restrict__ bsum, int nb) {
  __shared__ int tmp[256];
  const int v = (threadIdx.x < nb) ? bsum[threadIdx.x] : 0;
  tmp[threadIdx.x] = v;
  __syncthreads();
  for (int off = 1; off < 256; off <<= 1) {
    const int t = (threadIdx.x >= off) ? tmp[threadIdx.x - off] : 0;
    __syncthreads();
    tmp[threadIdx.x] += t;
    __syncthreads();
  }
  if (threadIdx.x < nb) bsum[threadIdx.x] = tmp[threadIdx.x] - v;
}
__global__ void scan_add(int* __restrict__ ptr, const int* __restrict__ bsum, int n, int E) {
  const int i = blockIdx.x * 256 + threadIdx.x;
  if (i < n) ptr[i] += bsum[blockIdx.x];
  if (i == 0) ptr[n] = E;
}
__global__ void fill_csr2(const int* __restrict__ src, const int* __restrict__ dst,
                          const float* __restrict__ dinv, const int* __restrict__ ptr,
                          const ushort_t* __restrict__ base16,
                          const ushort_t* __restrict__ rank,
                          int2* __restrict__ csr, int E, int M)
{
  const int e = blockIdx.x * 256 + threadIdx.x;
  if (e >= E) return;
  const int cs = (E + NB_H - 1) / NB_H;
  const int b = e / cs;
  const int s = src[e], d = dst[e];
  const int pos = ptr[d] + (int)base16[(size_t)b * M + d] + (int)rank[e];
  const float w = -dinv[s] * dinv[d];
  csr[pos] = make_int2(s, __float_as_int(w));
}

// fp8 decode+accumulate: 16 fp8 (uint4) scaled by ww into a[0..15]
#define ACCV(u, ww) { f32x2 t; \
  t = cvt2lo(u.x); a[0]  = fmaf(ww, t.x, a[0]);  a[1]  = fmaf(ww, t.y, a[1]);  \
  t = cvt2hi(u.x); a[2]  = fmaf(ww, t.x, a[2]);  a[3]  = fmaf(ww, t.y, a[3]);  \
  t = cvt2lo(u.y); a[4]  = fmaf(ww, t.x, a[4]);  a[5]  = fmaf(ww, t.y, a[5]);  \
  t = cvt2hi(u.y); a[6]  = fmaf(ww, t.x, a[6]);  a[7]  = fmaf(ww, t.y, a[7]);  \
  t = cvt2lo(u.z); a[8]  = fmaf(ww, t.x, a[8]);  a[9]  = fmaf(ww, t.y, a[9]);  \
  t = cvt2hi(u.z); a[10] = fmaf(ww, t.x, a[10]); a[11] = fmaf(ww, t.y, a[11]); \
  t = cvt2lo(u.w); a[12] = fmaf(ww, t.x, a[12]); a[13] = fmaf(ww, t.y, a[13]); \
  t = cvt2hi(u.w); a[14] = fmaf(ww, t.x, a[14]); a[15] = fmaf(ww, t.y, a[15]); }

// ---------------- gather128: eighth-wave, int2-packed CSR
__global__ __launch_bounds__(256) void gather128e(
    const u8* __restrict__ xf8, ushort_t* __restrict__ txb,
    const int* __restrict__ ptr, const int2* __restrict__ csr, int M)
{
  const int node = (blockIdx.x * 256 + threadIdx.x) >> 3;
  const int sub  = threadIdx.x & 7;
  if (node >= M) return;
  const int beg = ptr[node], end = ptr[node + 1];
  float a[16] = {};
  int p = beg;
  for (; p + 4 <= end; p += 4) {
    const int2 e0 = csr[p], e1 = csr[p + 1], e2 = csr[p + 2], e3 = csr[p + 3];
    const float w0 = __int_as_float(e0.y), w1 = __int_as_float(e1.y);
    const float w2 = __int_as_float(e2.y), w3 = __int_as_float(e3.y);
    const uint4 v0 = *(const uint4*)(xf8 + (size_t)e0.x * 128 + sub * 16);
    const uint4 v1 = *(const uint4*)(xf8 + (size_t)e1.x * 128 + sub * 16);
    const uint4 v2 = *(const uint4*)(xf8 + (size_t)e2.x * 128 + sub * 16);
    const uint4 v3 = *(const uint4*)(xf8 + (size_t)e3.x * 128 + sub * 16);
    ACCV(v0, w0) ACCV(v1, w1) ACCV(v2, w2) ACCV(v3, w3)
  }
  for (; p < end; ++p) {
    const int2 eq = csr[p]; const float wq = __int_as_float(eq.y);
    const uint4 v = *(const uint4*)(xf8 + (size_t)eq.x * 128 + sub * 16);
    ACCV(v, wq)
  }
  uint4 o1, o2;
  o1.x = (unsigned)f2bf(a[0])  | ((unsigned)f2bf(a[1])  << 16);
  o1.y = (unsigned)f2bf(a[2])  | ((unsigned)f2bf(a[3])  << 16);
  o1.z = (unsigned)f2bf(a[4])  | ((unsigned)f2bf(a[5])  << 16);
  o1.w = (unsigned)f2bf(a[6])  | ((unsigned)f2bf(a[7])  << 16);
  o2.x = (unsigned)f2bf(a[8])  | ((unsigned)f2bf(a[9])  << 16);
  o2.y = (unsigned)f2bf(a[10]) | ((unsigned)f2bf(a[11]) << 16);
  o2.z = (unsigned)f2bf(a[12]) | ((unsigned)f2bf(a[13]) << 16);
  o2.w = (unsigned)f2bf(a[14]) | ((unsigned)f2bf(a[15]) << 16);
  ushort_t* dstp = txb + (size_t)node * 128 + sub * 16;
  *(uint4*)dstp = o1;
  *(uint4*)(dstp + 8) = o2;
}

// ---------------- fused gather100 + x1 (eighth-wave, int2 CSR)
__global__ __launch_bounds__(256) void gather100e_x1(
    const u8* __restrict__ Brh, float* __restrict__ Ar,
    const int* __restrict__ ptr, const int2* __restrict__ csr, int M)
{
  const int node = (blockIdx.x * 256 + threadIdx.x) >> 3;
  const int sub  = threadIdx.x & 7;
  if (node >= M) return;
  const int beg = ptr[node], end = ptr[node + 1];
  float a[16] = {};
  int p = beg;
  for (; p + 4 <= end; p += 4) {
    const int2 e0 = csr[p], e1 = csr[p + 1], e2 = csr[p + 2], e3 = csr[p + 3];
    const float w0 = __int_as_float(e0.y), w1 = __int_as_float(e1.y);
    const float w2 = __int_as_float(e2.y), w3 = __int_as_float(e3.y);
    const uint4 v0 = *(const uint4*)(Brh + (size_t)e0.x * 128 + sub * 16);
    const uint4 v1 = *(const uint4*)(Brh + (size_t)e1.x * 128 + sub * 16);
    const uint4 v2 = *(const uint4*)(Brh + (size_t)e2.x * 128 + sub * 16);
    const uint4 v3 = *(const uint4*)(Brh + (size_t)e3.x * 128 + sub * 16);
    ACCV(v0, w0) ACCV(v1, w1) ACCV(v2, w2) ACCV(v3, w3)
  }
  for (; p < end; ++p) {
    const int2 eq = csr[p]; const float wq = __int_as_float(eq.y);
    const uint4 v = *(const uint4*)(Brh + (size_t)eq.x * 128 + sub * 16);
    ACCV(v, wq)
  }
  float* dstp = Ar + (size_t)node * 128 + sub * 16;
#pragma unroll
  for (int q = 0; q < 4; ++q) {
    float4 b = *(const float4*)(dstp + q * 4);
    b.x = fmaxf(b.x + a[q * 4 + 0], 0.f);
    b.y = fmaxf(b.y + a[q * 4 + 1], 0.f);
    b.z = fmaxf(b.z + a[q * 4 + 2], 0.f);
    b.w = fmaxf(b.w + a[q * 4 + 3], 0.f);
    *(float4*)(dstp + q * 4) = b;
  }
}
#undef ACCV

// ---------------- loss: eighth-wave per pair, 2-way ILP (unchanged)
#define DOTV(uu, vv, s) { f32x2 p_, q_; \
  p_ = cvt2lo(uu.x); q_ = cvt2lo(vv.x); s = fmaf(p_.x, q_.x, s); s = fmaf(p_.y, q_.y, s); \
  p_ = cvt2hi(uu.x); q_ = cvt2hi(vv.x); s = fmaf(p_.x, q_.x, s); s = fmaf(p_.y, q_.y, s); \
  p_ = cvt2lo(uu.y); q_ = cvt2lo(vv.y); s = fmaf(p_.x, q_.x, s); s = fmaf(p_.y, q_.y, s); \
  p_ = cvt2hi(uu.y); q_ = cvt2hi(vv.y); s = fmaf(p_.x, q_.x, s); s = fmaf(p_.y, q_.y, s); \
  p_ = cvt2lo(uu.z); q_ = cvt2lo(vv.z); s = fmaf(p_.x, q_.x, s); s = fmaf(p_.y, q_.y, s); \
  p_ = cvt2hi(uu.z); q_ = cvt2hi(vv.z); s = fmaf(p_.x, q_.x, s); s = fmaf(p_.y, q_.y, s); \
  p_ = cvt2lo(uu.w); q_ = cvt2lo(vv.w); s = fmaf(p_.x, q_.x, s); s = fmaf(p_.y, q_.y, s); \
  p_ = cvt2hi(uu.w); q_ = cvt2hi(vv.w); s = fmaf(p_.x, q_.x, s); s = fmaf(p_.y, q_.y, s); }

__global__ __launch_bounds__(256) void loss_fp8(
    const u8* __restrict__ zf8, const int* __restrict__ ep,
    const int* __restrict__ en, int P, float* __restrict__ acc)
{
  __shared__ float red[8];
  const int tid = threadIdx.x;
  const int lane = tid & 63, wib = tid >> 6;
  const int sub = tid & 7;
  const int slot0 = blockIdx.x * 32 + (tid >> 3);
  const int step = gridDim.x * 32;
  float tp = 0.f, tn = 0.f;
  int g = slot0;
  for (; g + step < 2 * P; g += 2 * step) {
    const int gA = g, gB = g + step;
    const int negA = (gA >= P), negB = (gB >= P);
    const int pA = negA ? gA - P : gA, pB = negB ? gB - P : gB;
    const int* iA = negA ? en : ep;
    const int* iB = negB ? en : ep;
    const int naA = iA[pA], nbA = iA[P + pA];
    const int naB = iB[pB], nbB = iB[P + pB];
    const uint4 ra1 = *(const uint4*)(zf8 + (size_t)naA * 128 + sub * 16);
    const uint4 rb1 = *(const uint4*)(zf8 + (size_t)nbA * 128 + sub * 16);
    const uint4 ra2 = *(const uint4*)(zf8 + (size_t)naB * 128 + sub * 16);
    const uint4 rb2 = *(const uint4*)(zf8 + (size_t)nbB * 128 + sub * 16);
    float sA = 0.f, sB = 0.f;
    DOTV(ra1, rb1, sA)
    DOTV(ra2, rb2, sB)
#pragma unroll
    for (int off = 4; off; off >>= 1) {
      sA += __shfl_down(sA, off, 8);
      sB += __shfl_down(sB, off, 8);
    }
    if (sub == 0) {
      const float gA_ = 1.f / (1.f + expf(-sA));
      if (negA) tn += logf(1.f - gA_ + 1e-15f); else tp += logf(gA_ + 1e-15f);
      const float gB_ = 1.f / (1.f + expf(-sB));
      if (negB) tn += logf(1.f - gB_ + 1e-15f); else tp += logf(gB_ + 1e-15f);
    }
  }
  if (g < 2 * P) {
    const int neg = (g >= P);
    const int p = neg ? g - P : g;
    const int* ia = neg ? en : ep;
    const int na = ia[p], nb = ia[P + p];
    const uint4 ra = *(const uint4*)(zf8 + (size_t)na * 128 + sub * 16);
    const uint4 rb = *(const uint4*)(zf8 + (size_t)nb * 128 + sub * 16);
    float s = 0.f;
    DOTV(ra, rb, s)
#pragma unroll
    for (int off = 4; off; off >>= 1) s += __shfl_down(s, off, 8);
    if (sub == 0) {
      const float sig = 1.f / (1.f + expf(-s));
      if (neg) tn += logf(1.f - sig + 1e-15f); else tp += logf(sig + 1e-15f);
    }
  }
  tp += __shfl_down(tp, 32, 64); tn += __shfl_down(tn, 32, 64);
  tp += __shfl_down(tp, 16, 64); tn += __shfl_down(tn, 16, 64);
  tp += __shfl_down(tp, 8, 64);  tn += __shfl_down(tn, 8, 64);
  if (lane == 0) { red[wib] = tp; red[4 + wib] = tn; }
  __syncthreads();
  if (tid == 0) {
    atomicAdd(acc + 0, red[0] + red[1] + red[2] + red[3]);
    atomicAdd(acc + 1, red[4] + red[5] + red[6] + red[7]);
  }
}
#undef DOTV

// ---------------- fused gather2 + final (int2 CSR)
__global__ void gather2_final(
    const float* __restrict__ t1, const float* __restrict__ t0,
    const int* __restrict__ ptr, const int2* __restrict__ csr,
    const float* __restrict__ accs,
    const float* __restrict__ c1, const float* __restrict__ c2,
    float* __restrict__ out, int M, float invP)
{
  const int i = blockIdx.x * blockDim.x + threadIdx.x;
  if (i < M) {
    float a0 = 0.f, a1 = 0.f;
    const int beg = ptr[i], end = ptr[i + 1];
    int p = beg;
    for (; p + 4 <= end; p += 4) {
      const int2 e0 = csr[p], e1 = csr[p + 1], e2 = csr[p + 2], e3 = csr[p + 3];
      const float w0 = __int_as_float(e0.y), w1 = __int_as_float(e1.y);
      const float w2 = __int_as_float(e2.y), w3 = __int_as_float(e3.y);
      const float2 v0 = *(const float2*)(t1 + (size_t)e0.x * 2);
      const float2 v1 = *(const float2*)(t1 + (size_t)e1.x * 2);
      const float2 v2 = *(const float2*)(t1 + (size_t)e2.x * 2);
      const float2 v3 = *(const float2*)(t1 + (size_t)e3.x * 2);
      a0 = fmaf(w0, v0.x, a0); a1 = fmaf(w0, v0.y, a1);
      a0 = fmaf(w1, v1.x, a0); a1 = fmaf(w1, v1.y, a1);
      a0 = fmaf(w2, v2.x, a0); a1 = fmaf(w2, v2.y, a1);
      a0 = fmaf(w3, v3.x, a0); a1 = fmaf(w3, v3.y, a1);
    }
    for (; p < end; ++p) {
      const int2 eq = csr[p]; const float wq = __int_as_float(eq.y);
      const float2 v = *(const float2*)(t1 + (size_t)eq.x * 2);
      a0 = fmaf(wq, v.x, a0); a1 = fmaf(wq, v.y, a1);
    }
    const float2 base = *(const float2*)(t0 + (size_t)i * 2);
    *(float2*)(out + (size_t)i * 2) = make_float2(base.x + a0, base.y + a1);
  }
  if (i == 0) {
    out[2 * M + 0] = -(accs[0] + accs[1]) * invP;
    out[2 * M + 1] = c1[0];
    out[2 * M + 2] = c2[0];
  }
}

extern "C" void kernel_launch(void* const* d_in, const int* in_sizes, int n_in,
                              void* d_out, int out_size, void* d_ws, size_t ws_size,
                              hipStream_t stream)
{
  const float* x   = (const float*)d_in[0];
  const int*   ei  = (const int*)d_in[1];
  const int*   ep  = (const int*)d_in[2];
  const int*   en  = (const int*)d_in[3];
  const float* W1  = (const float*)d_in[4];
  const float* b1  = (const float*)d_in[5];
  const float* W2  = (const float*)d_in[6];
  const float* b2  = (const float*)d_in[7];
  const float* W3  = (const float*)d_in[8];
  const float* b3  = (const float*)d_in[9];
  const float* l1W = (const float*)d_in[10];
  const float* l1b = (const float*)d_in[11];
  const float* l2W = (const float*)d_in[12];
  const float* l2b = (const float*)d_in[13];
  const float* c1  = (const float*)d_in[14];
  const float* c2  = (const float*)d_in[15];
  float* out = (float*)d_out;

  const int M = in_sizes[0] / 128;  // 50000
  const int E = in_sizes[1] / 2;    // 800000
  const int P = in_sizes[2] / 2;    // 400000
  const int* src = ei;
  const int* dst = ei + E;
  const int nb_scan = (M + 255) / 256;

  float* ws = (float*)d_ws;
  size_t o = 0;
  float*    dinv = ws + o;            o += 50176;
  int*      cnt  = (int*)(ws + o);    o += (size_t)M;
  int*      ptr  = (int*)(ws + o);    o += (size_t)M + 8;
  int*      bsum = (int*)(ws + o);    o += 256;
  int2*     csr  = (int2*)(ws + o);   o += (size_t)E * 2;        // packed {src, wbits}
  ushort_t* partS = (ushort_t*)(ws + o); o += (size_t)NB_H * M / 2;  // u16 [NB_H][M]
  ushort_t* partD = (ushort_t*)(ws + o); o += (size_t)NB_H * M / 2;
  ushort_t* rank  = (ushort_t*)(ws + o); o += (size_t)E / 2;
  ushort_t* xb   = (ushort_t*)(ws + o); o += (size_t)M * 64;   // bf16 [M][128]
  u8*       xf8  = (u8*)(ws + o);     o += (size_t)M * 32;     // fp8 [M][128]
  ushort_t* tx0b = (ushort_t*)(ws + o); o += (size_t)M * 64;   // bf16 [M][128]
  ushort_t* W1t  = (ushort_t*)(ws + o); o += 40960;            // [320][256]
  ushort_t* W2t  = (ushort_t*)(ws + o); o += 35840;            // [224][320]
  ushort_t* Wlt  = (ushort_t*)(ws + o); o += 14336;            // [224][128]
  ushort_t* h    = (ushort_t*)(ws + o); o += (size_t)M * 160;  // bf16 [M][320]
  float*    Ar   = ws + o;            o += (size_t)M * 128;    // f32 stride128 -> x1
  u8*       Brh  = (u8*)(ws + o);     o += (size_t)M * 32;     // fp8 [M][128]
  u8*       zf8  = (u8*)(ws + o);     o += (size_t)M * 32;     // fp8 [M][128]
  float*    t0   = ws + o;            o += (size_t)M * 2;
  float*    t1   = ws + o;            o += (size_t)M * 2;
  float*    accs = ws + o;            o += 8;
  ushort_t* base16 = partS;  // alias: partS dead after reduce_hist

  hipMemsetAsync(accs, 0, 2 * 4, stream);
  hipMemsetAsync(Brh,  0, (size_t)M * 128, stream);  // pad cols must decode to 0
  hipMemsetAsync(zf8,  0, (size_t)M * 128, stream);

  // packing (independent, early)
  cvt_x_kernel<<<(M * 32 + 255) / 256, 256, 0, stream>>>(x, xb, xf8, M * 32);
  pack_all<<<(182272 + 255) / 256, 256, 0, stream>>>(W1, W2, l1W, l2W, W1t, W2t, Wlt);

  // CSR build (no global atomics)
  hist_rank<<<NB_H, 256, 0, stream>>>(src, dst, E, M, partS, partD, rank);
  reduce_hist<<<(M + 255) / 256, 256, 0, stream>>>(partS, partD, dinv, cnt, M);
  scan_local<<<nb_scan, 256, 0, stream>>>(cnt, ptr, bsum, M);
  scan_bsum<<<1, 256, 0, stream>>>(bsum, nb_scan);
  scan_add<<<nb_scan, 256, 0, stream>>>(ptr, bsum, M, E);
  base_tab<<<(M + 255) / 256, 256, 0, stream>>>(partD, base16, M);
  fill_csr2<<<(E + 255) / 256, 256, 0, stream>>>(src, dst, dinv, ptr, base16, rank, csr, E, M);

  const int gB = (M + 63) / 64;
  const int gE8 = (M * 8 + 255) / 256;

  // conv1
  gather128e<<<gE8, 256, 0, stream>>>(xf8, tx0b, ptr, csr, M);
  gemm_mfma<0, 320, 256><<<gB, 256, 0, stream>>>(
      xb, tx0b, W1t, b1, nullptr, nullptr, nullptr, nullptr, h, nullptr, nullptr, nullptr, M);

  // conv2 (propagate after GEMM at 100)
  gemm_mfma<1, 224, 320><<<gB, 256, 0, stream>>>(
      h, nullptr, W2t, b2, nullptr, nullptr, nullptr, nullptr, Ar, Brh, nullptr, nullptr, M);
  gather100e_x1<<<gE8, 256, 0, stream>>>(Brh, Ar, ptr, csr, M);

  // lins + fused w3 (x2 never materialized)
  gemm_mfma<2, 224, 128><<<gB, 256, 0, stream>>>(
      xb, nullptr, Wlt, l1b, l2b, Ar /*x1*/, W3, b3, nullptr, zf8, t0, t1, M);

  // loss
  loss_fp8<<<2048, 256, 0, stream>>>(zf8, ep, en, P, accs);

  // conv3 propagation + final
  gather2_final<<<(M + 255) / 256, 256, 0, stream>>>(t1, t0, ptr, csr,
                                                     accs, c1, c2, out, M, 1.0f / (float)P);
}

// Round 9
// 483.808 us; speedup vs baseline: 1.1735x; 1.1735x over previous
//
#include <hip/hip_runtime.h>
#include <math.h>

// MTGCN R7: atomic-free CSR build, correctly parallelized.
//  hist2: 256 blocks (1/CU) x 3125-edge chunks; bins packed 2-per-u32 in 50KB LDS,
//  4 phases ({src,dst} x 2 ranges); dst phases record per-edge rank from LDS-atomic
//  return. reduce_base fuses partial-sum (dinv,cnt) + in-place exclusive block-scan
//  (base table). fill_csr2: pos = ptr[d]+base+rank, no atomics, packed int2 CSR.
//  Partial tables alias h/Ar (dead until later GEMMs).
// Rest as R5b/R6: bf16 MFMA GEMMs, fp8 128B-line rows, eighth-wave gathers/loss.

typedef unsigned short ushort_t;
typedef unsigned char u8;
typedef __attribute__((ext_vector_type(8))) __bf16 bf16x8;
typedef __attribute__((ext_vector_type(8))) short s16x8;
typedef __attribute__((ext_vector_type(4))) float f32x4;
typedef __attribute__((ext_vector_type(2))) float f32x2;

#define NB_H 256     // histogram blocks (1 per CU)
#define HW 12500     // LDS words per range (25000 bins packed 2/u32)
#define PW 25000     // packed words per block in partial tables

__device__ __forceinline__ f32x4 mfma16x16x32(s16x8 a, s16x8 b, f32x4 c) {
  return __builtin_amdgcn_mfma_f32_16x16x32_bf16(
      __builtin_bit_cast(bf16x8, a), __builtin_bit_cast(bf16x8, b), c, 0, 0, 0);
}
__device__ __forceinline__ ushort_t f2bf(float f) {
  union { float f; unsigned u; } c; c.f = f;
  unsigned r = (c.u + 0x7FFFu + ((c.u >> 16) & 1u)) >> 16;
  return (ushort_t)r;
}
__device__ __forceinline__ f32x2 cvt2lo(unsigned u) {
  return __builtin_amdgcn_cvt_pk_f32_fp8((int)u, false);
}
__device__ __forceinline__ f32x2 cvt2hi(unsigned u) {
  return __builtin_amdgcn_cvt_pk_f32_fp8((int)u, true);
}
__device__ __forceinline__ u8 f2fp8(float f) {
  return (u8)(__builtin_amdgcn_cvt_pk_fp8_f32(f, 0.f, 0, false) & 0xff);
}

// =======================================================================
// MFMA GEMM (unchanged from R5b/R6)
// =======================================================================
template<int VAR, int NT, int KTOT>
__global__ __launch_bounds__(256) void gemm_mfma(
    const ushort_t* __restrict__ A0, const ushort_t* __restrict__ A1,
    const ushort_t* __restrict__ Wt,
    const float* __restrict__ bias0, const float* __restrict__ bias1,
    const float* __restrict__ x1,
    const float* __restrict__ W3c, const float* __restrict__ b3c,
    void* __restrict__ out0, void* __restrict__ out1,
    float* __restrict__ t0g, float* __restrict__ t1g, int M)
{
  constexpr int NF = NT / 32;
  __shared__ __align__(16) ushort_t As[64 * 40];
  __shared__ __align__(16) ushort_t Bs[NT * 40];
  __shared__ float w3s[400];
  const int tid  = threadIdx.x;
  const int lane = tid & 63, w = tid >> 6;
  const int m0 = blockIdx.x * 64;
  const int wm = (w & 1) * 32, wn = (w >> 1) * (NT / 2);
  if (VAR == 2) { for (int i = tid; i < 400; i += 256) w3s[i] = W3c[i]; }
  f32x4 acc[2][NF];
#pragma unroll
  for (int i = 0; i < 2; ++i)
#pragma unroll
    for (int j = 0; j < NF; ++j) acc[i][j] = (f32x4){0.f, 0.f, 0.f, 0.f};

  for (int k0 = 0; k0 < KTOT; k0 += 32) {
    { // A stage
      const int r = tid >> 2, c8 = (tid & 3) * 8;
      const int gm = m0 + r;
      uint4 v = {0u, 0u, 0u, 0u};
      if (gm < M) {
        const ushort_t* srcp;
        if (VAR == 0) srcp = (k0 < 128) ? A0 + (size_t)gm * 128 + k0 + c8
                                        : A1 + (size_t)gm * 128 + (k0 - 128) + c8;
        else if (VAR == 1) srcp = A0 + (size_t)gm * 320 + k0 + c8;
        else srcp = A0 + (size_t)gm * 128 + k0 + c8;
        v = *(const uint4*)srcp;
      }
      *(uint4*)&As[r * 40 + c8] = v;
    }
    { // B stage
      const int c8 = (tid & 3) * 8;
#pragma unroll
      for (int i = 0; i < (NT * 4 + 255) / 256; ++i) {
        const int r = (tid >> 2) + i * 64;
        if (r < NT)
          *(uint4*)&Bs[r * 40 + c8] = *(const uint4*)(Wt + (size_t)r * KTOT + k0 + c8);
      }
    }
    __syncthreads();
    s16x8 af[2], bfr[NF];
#pragma unroll
    for (int mi = 0; mi < 2; ++mi)
      af[mi] = *(const s16x8*)&As[(wm + mi * 16 + (lane & 15)) * 40 + (lane >> 4) * 8];
#pragma unroll
    for (int ni = 0; ni < NF; ++ni)
      bfr[ni] = *(const s16x8*)&Bs[(wn + ni * 16 + (lane & 15)) * 40 + (lane >> 4) * 8];
#pragma unroll
    for (int mi = 0; mi < 2; ++mi)
#pragma unroll
      for (int ni = 0; ni < NF; ++ni)
        acc[mi][ni] = mfma16x16x32(af[mi], bfr[ni], acc[mi][ni]);
    __syncthreads();
  }

  if (VAR == 2) {
#pragma unroll
    for (int mi = 0; mi < 2; ++mi)
#pragma unroll
      for (int r = 0; r < 4; ++r) {
        const int gRow = m0 + wm + mi * 16 + ((lane >> 4) << 2) + r;
        float p0 = 0.f, p1 = 0.f, p2 = 0.f, p3 = 0.f;
#pragma unroll
        for (int ni = 0; ni < NF; ++ni) {
          const int col = wn + ni * 16 + (lane & 15);
          const float v = acc[mi][ni][r];
          if (gRow < M) {
            if (col < 100) {
              const float x2v = x1[(size_t)gRow * 128 + col] + fmaxf(v + bias0[col], 0.f);
              p0 = fmaf(x2v, w3s[col * 2 + 0], p0);
              p1 = fmaf(x2v, w3s[col * 2 + 1], p1);
              p2 = fmaf(x2v, w3s[200 + col * 2 + 0], p2);
              p3 = fmaf(x2v, w3s[200 + col * 2 + 1], p3);
            } else if (col < 200) {
              const int c = col - 100;
              ((u8*)out1)[(size_t)gRow * 128 + c] =
                  f2fp8(x1[(size_t)gRow * 128 + c] + fmaxf(v + bias1[c], 0.f));
            }
          }
        }
        if (wn == 0) {
#pragma unroll
          for (int off = 8; off; off >>= 1) {
            p0 += __shfl_down(p0, off, 16);
            p1 += __shfl_down(p1, off, 16);
            p2 += __shfl_down(p2, off, 16);
            p3 += __shfl_down(p3, off, 16);
          }
          if ((lane & 15) == 0 && gRow < M) {
            t0g[(size_t)gRow * 2 + 0] = p0 + b3c[0];
            t0g[(size_t)gRow * 2 + 1] = p1 + b3c[1];
            t1g[(size_t)gRow * 2 + 0] = p2;
            t1g[(size_t)gRow * 2 + 1] = p3;
          }
        }
      }
  } else {
#pragma unroll
    for (int mi = 0; mi < 2; ++mi)
#pragma unroll
      for (int ni = 0; ni < NF; ++ni)
#pragma unroll
        for (int r = 0; r < 4; ++r) {
          const int gRow = m0 + wm + mi * 16 + ((lane >> 4) << 2) + r;
          const int col  = wn + ni * 16 + (lane & 15);
          if (gRow >= M) continue;
          const float v = acc[mi][ni][r];
          if (VAR == 0) {
            ushort_t* h = (ushort_t*)out0;
            h[(size_t)gRow * 320 + col] = (col < 300) ? f2bf(fmaxf(v + bias0[col], 0.f))
                                                      : (ushort_t)0;
          } else {
            if (col < 100) ((float*)out0)[(size_t)gRow * 128 + col] = v + bias0[col];
            else if (col < 200) ((u8*)out1)[(size_t)gRow * 128 + (col - 100)] = f2fp8(v);
          }
        }
  }
}

// ---------------- packing / conversion ----------------
__global__ void cvt_x_kernel(const float* __restrict__ x, ushort_t* __restrict__ xb,
                             u8* __restrict__ xf8, int n4) {
  const int i = blockIdx.x * 256 + threadIdx.x;
  if (i < n4) {
    const float4 v = ((const float4*)x)[i];
    ushort4 o; o.x = f2bf(v.x); o.y = f2bf(v.y); o.z = f2bf(v.z); o.w = f2bf(v.w);
    ((ushort4*)xb)[i] = o;
    int p = 0;
    p = __builtin_amdgcn_cvt_pk_fp8_f32(v.x, v.y, p, false);
    p = __builtin_amdgcn_cvt_pk_fp8_f32(v.z, v.w, p, true);
    ((unsigned*)xf8)[i] = (unsigned)p;
  }
}
__global__ void pack_all(const float* __restrict__ W1, const float* __restrict__ W2,
                         const float* __restrict__ l1W, const float* __restrict__ l2W,
                         ushort_t* __restrict__ W1t, ushort_t* __restrict__ W2t,
                         ushort_t* __restrict__ Wlt) {
  const int i = blockIdx.x * 256 + threadIdx.x;
  if (i < 81920) {                       // W1t [320][256]
    const int n = i >> 8, k = i & 255;
    float v = 0.f;
    if (n < 300) v = (k < 128) ? W1[k * 300 + n] : W1[38400 + (k - 128) * 300 + n];
    W1t[i] = f2bf(v);
  } else if (i < 153600) {               // W2t [224][320]
    const int j = i - 81920;
    const int n = j / 320, k = j - n * 320;
    float v = 0.f;
    if (n < 200 && k < 300) v = W2[(n < 100 ? 0 : 30000) + k * 100 + (n % 100)];
    W2t[j] = f2bf(v);
  } else if (i < 182272) {               // Wlt [224][128]
    const int j = i - 153600;
    const int n = j >> 7, k = j & 127;
    float v = 0.f;
    if (n < 100) v = l1W[n * 128 + k];
    else if (n < 200) v = l2W[(n - 100) * 128 + k];
    Wlt[j] = f2bf(v);
  }
}

// ---------------- histogram + rank: 256 blocks, packed 2-per-u32 bins ----------------
__global__ __launch_bounds__(256) void hist2(
    const int* __restrict__ src, const int* __restrict__ dst, int E, int M,
    unsigned* __restrict__ partS, unsigned* __restrict__ partD,
    ushort_t* __restrict__ rank)
{
  __shared__ unsigned hist[HW];
  const int b = blockIdx.x;
  const int cs = (E + NB_H - 1) / NB_H;
  const int e0 = b * cs;
  const int e1 = (e0 + cs < E) ? e0 + cs : E;
  for (int isD = 0; isD < 2; ++isD) {
    const int* keys = isD ? dst : src;
    unsigned* part = isD ? partD : partS;
    for (int r = 0; r < 2; ++r) {
      const int klo = r * 2 * HW;   // node range [klo, klo+25000)
      for (int i = threadIdx.x; i < HW; i += 256) hist[i] = 0;
      __syncthreads();
      for (int e = e0 + threadIdx.x; e < e1; e += 256) {
        const int k = keys[e] - klo;
        if ((unsigned)k < (unsigned)(2 * HW)) {
          const unsigned old = atomicAdd(&hist[k >> 1], (k & 1) ? 0x10000u : 1u);
          if (isD) rank[e] = (ushort_t)((old >> ((k & 1) * 16)) & 0xffffu);
        }
      }
      __syncthreads();
      for (int i = threadIdx.x; i < HW; i += 256)
        part[(size_t)b * PW + r * HW + i] = hist[i];
      __syncthreads();
    }
  }
}

// partials -> dinv (1/sqrt out-deg), cnt (in-deg); partD -> in-place exclusive
// block-scan (base table, packed u16 pairs).
__global__ void reduce_base(const unsigned* __restrict__ partS,
                            unsigned* __restrict__ partD,
                            float* __restrict__ dinv, int* __restrict__ cnt, int M)
{
  const int i = blockIdx.x * 256 + threadIdx.x;  // packed pair index
  if (i >= PW) return;
  unsigned s0 = 0, s1 = 0;
  for (int b = 0; b < NB_H; ++b) {
    const unsigned v = partS[(size_t)b * PW + i];
    s0 += v & 0xffffu; s1 += v >> 16;
  }
  unsigned r0 = 0, r1 = 0;
  for (int b = 0; b < NB_H; ++b) {
    const unsigned v = partD[(size_t)b * PW + i];
    partD[(size_t)b * PW + i] = r0 | (r1 << 16);
    r0 += v & 0xffffu; r1 += v >> 16;
  }
  const int k = 2 * i;
  if (k < M) {
    dinv[k] = s0 ? 1.f / sqrtf((float)s0) : 0.f;
    cnt[k] = (int)r0;
  }
  if (k + 1 < M) {
    dinv[k + 1] = s1 ? 1.f / sqrtf((float)s1) : 0.f;
    cnt[k + 1] = (int)r1;
  }
}

// ---------------- scan (unchanged)
__global__ void scan_local(const int* __restrict__ cnt, int* __restrict__ ptr,
                           int* __restrict__ bsum, int n)
{
  __shared__ int tmp[256];
  const int i = blockIdx.x * 256 + threadIdx.x;
  const int v = (i < n) ? cnt[i] : 0;
  tmp[threadIdx.x] = v;
  __syncthreads();
  for (int off = 1; off < 256; off <<= 1) {
    const int t = (threadIdx.x >= off) ? tmp[threadIdx.x - off] : 0;
    __syncthreads();
    tmp[threadIdx.x] += t;
    __syncthreads();
  }
  if (i < n) ptr[i] = tmp[threadIdx.x] - v;
  if (threadIdx.x == 255) bsum[blockIdx.x] = tmp[255];
}
__global__ void scan_bsum(int* __restrict__ bsum, int nb) {
  __shared__ int tmp[256];
  const int v = (threadIdx.x < nb) ? bsum[threadIdx.x] : 0;
  tmp[threadIdx.x] = v;
  __syncthreads();
  for (int off = 1; off < 256; off <<= 1) {
    const int t = (threadIdx.x >= off) ? tmp[threadIdx.x - off] : 0;
    __syncthreads();
    tmp[threadIdx.x] += t;
    __syncthreads();
  }
  if (threadIdx.x < nb) bsum[threadIdx.x] = tmp[threadIdx.x] - v;
}
__global__ void scan_add(int* __restrict__ ptr, const int* __restrict__ bsum, int n, int E) {
  const int i = blockIdx.x * 256 + threadIdx.x;
  if (i < n) ptr[i] += bsum[blockIdx.x];
  if (i == 0) ptr[n] = E;
}

// ---------------- atomic-free fill: pos = ptr[d] + base[b][d] + rank[e]
__global__ void fill_csr2(const int* __restrict__ src, const int* __restrict__ dst,
                          const float* __restrict__ dinv, const int* __restrict__ ptr,
                          const unsigned* __restrict__ base32,
                          const ushort_t* __restrict__ rank,
                          int2* __restrict__ csr, int E)
{
  const int e = blockIdx.x * 256 + threadIdx.x;
  if (e >= E) return;
  const int cs = (E + NB_H - 1) / NB_H;
  const int b = e / cs;
  const int s = src[e], d = dst[e];
  const unsigned bv = base32[(size_t)b * PW + (d >> 1)];
  const int base = (int)((bv >> ((d & 1) * 16)) & 0xffffu);
  const int pos = ptr[d] + base + (int)rank[e];
  const float w = -dinv[s] * dinv[d];
  csr[pos] = make_int2(s, __float_as_int(w));
}

// fp8 decode+accumulate: 16 fp8 (uint4) scaled by ww into a[0..15]
#define ACCV(u, ww) { f32x2 t; \
  t = cvt2lo(u.x); a[0]  = fmaf(ww, t.x, a[0]);  a[1]  = fmaf(ww, t.y, a[1]);  \
  t = cvt2hi(u.x); a[2]  = fmaf(ww, t.x, a[2]);  a[3]  = fmaf(ww, t.y, a[3]);  \
  t = cvt2lo(u.y); a[4]  = fmaf(ww, t.x, a[4]);  a[5]  = fmaf(ww, t.y, a[5]);  \
  t = cvt2hi(u.y); a[6]  = fmaf(ww, t.x, a[6]);  a[7]  = fmaf(ww, t.y, a[7]);  \
  t = cvt2lo(u.z); a[8]  = fmaf(ww, t.x, a[8]);  a[9]  = fmaf(ww, t.y, a[9]);  \
  t = cvt2hi(u.z); a[10] = fmaf(ww, t.x, a[10]); a[11] = fmaf(ww, t.y, a[11]); \
  t = cvt2lo(u.w); a[12] = fmaf(ww, t.x, a[12]); a[13] = fmaf(ww, t.y, a[13]); \
  t = cvt2hi(u.w); a[14] = fmaf(ww, t.x, a[14]); a[15] = fmaf(ww, t.y, a[15]); }

// ---------------- gather128: eighth-wave, int2-packed CSR
__global__ __launch_bounds__(256) void gather128e(
    const u8* __restrict__ xf8, ushort_t* __restrict__ txb,
    const int* __restrict__ ptr, const int2* __restrict__ csr, int M)
{
  const int node = (blockIdx.x * 256 + threadIdx.x) >> 3;
  const int sub  = threadIdx.x & 7;
  if (node >= M) return;
  const int beg = ptr[node], end = ptr[node + 1];
  float a[16] = {};
  int p = beg;
  for (; p + 4 <= end; p += 4) {
    const int2 e0 = csr[p], e1 = csr[p + 1], e2 = csr[p + 2], e3 = csr[p + 3];
    const float w0 = __int_as_float(e0.y), w1 = __int_as_float(e1.y);
    const float w2 = __int_as_float(e2.y), w3 = __int_as_float(e3.y);
    const uint4 v0 = *(const uint4*)(xf8 + (size_t)e0.x * 128 + sub * 16);
    const uint4 v1 = *(const uint4*)(xf8 + (size_t)e1.x * 128 + sub * 16);
    const uint4 v2 = *(const uint4*)(xf8 + (size_t)e2.x * 128 + sub * 16);
    const uint4 v3 = *(const uint4*)(xf8 + (size_t)e3.x * 128 + sub * 16);
    ACCV(v0, w0) ACCV(v1, w1) ACCV(v2, w2) ACCV(v3, w3)
  }
  for (; p < end; ++p) {
    const int2 eq = csr[p]; const float wq = __int_as_float(eq.y);
    const uint4 v = *(const uint4*)(xf8 + (size_t)eq.x * 128 + sub * 16);
    ACCV(v, wq)
  }
  uint4 o1, o2;
  o1.x = (unsigned)f2bf(a[0])  | ((unsigned)f2bf(a[1])  << 16);
  o1.y = (unsigned)f2bf(a[2])  | ((unsigned)f2bf(a[3])  << 16);
  o1.z = (unsigned)f2bf(a[4])  | ((unsigned)f2bf(a[5])  << 16);
  o1.w = (unsigned)f2bf(a[6])  | ((unsigned)f2bf(a[7])  << 16);
  o2.x = (unsigned)f2bf(a[8])  | ((unsigned)f2bf(a[9])  << 16);
  o2.y = (unsigned)f2bf(a[10]) | ((unsigned)f2bf(a[11]) << 16);
  o2.z = (unsigned)f2bf(a[12]) | ((unsigned)f2bf(a[13]) << 16);
  o2.w = (unsigned)f2bf(a[14]) | ((unsigned)f2bf(a[15]) << 16);
  ushort_t* dstp = txb + (size_t)node * 128 + sub * 16;
  *(uint4*)dstp = o1;
  *(uint4*)(dstp + 8) = o2;
}

// ---------------- fused gather100 + x1 (eighth-wave, int2 CSR)
__global__ __launch_bounds__(256) void gather100e_x1(
    const u8* __restrict__ Brh, float* __restrict__ Ar,
    const int* __restrict__ ptr, const int2* __restrict__ csr, int M)
{
  const int node = (blockIdx.x * 256 + threadIdx.x) >> 3;
  const int sub  = threadIdx.x & 7;
  if (node >= M) return;
  const int beg = ptr[node], end = ptr[node + 1];
  float a[16] = {};
  int p = beg;
  for (; p + 4 <= end; p += 4) {
    const int2 e0 = csr[p], e1 = csr[p + 1], e2 = csr[p + 2], e3 = csr[p + 3];
    const float w0 = __int_as_float(e0.y), w1 = __int_as_float(e1.y);
    const float w2 = __int_as_float(e2.y), w3 = __int_as_float(e3.y);
    const uint4 v0 = *(const uint4*)(Brh + (size_t)e0.x * 128 + sub * 16);
    const uint4 v1 = *(const uint4*)(Brh + (size_t)e1.x * 128 + sub * 16);
    const uint4 v2 = *(const uint4*)(Brh + (size_t)e2.x * 128 + sub * 16);
    const uint4 v3 = *(const uint4*)(Brh + (size_t)e3.x * 128 + sub * 16);
    ACCV(v0, w0) ACCV(v1, w1) ACCV(v2, w2) ACCV(v3, w3)
  }
  for (; p < end; ++p) {
    const int2 eq = csr[p]; const float wq = __int_as_float(eq.y);
    const uint4 v = *(const uint4*)(Brh + (size_t)eq.x * 128 + sub * 16);
    ACCV(v, wq)
  }
  float* dstp = Ar + (size_t)node * 128 + sub * 16;
#pragma unroll
  for (int q = 0; q < 4; ++q) {
    float4 b = *(const float4*)(dstp + q * 4);
    b.x = fmaxf(b.x + a[q * 4 + 0], 0.f);
    b.y = fmaxf(b.y + a[q * 4 + 1], 0.f);
    b.z = fmaxf(b.z + a[q * 4 + 2], 0.f);
    b.w = fmaxf(b.w + a[q * 4 + 3], 0.f);
    *(float4*)(dstp + q * 4) = b;
  }
}
#undef ACCV

// ---------------- loss: eighth-wave per pair, 2-way ILP
#define DOTV(uu, vv, s) { f32x2 p_, q_; \
  p_ = cvt2lo(uu.x); q_ = cvt2lo(vv.x); s = fmaf(p_.x, q_.x, s); s = fmaf(p_.y, q_.y, s); \
  p_ = cvt2hi(uu.x); q_ = cvt2hi(vv.x); s = fmaf(p_.x, q_.x, s); s = fmaf(p_.y, q_.y, s); \
  p_ = cvt2lo(uu.y); q_ = cvt2lo(vv.y); s = fmaf(p_.x, q_.x, s); s = fmaf(p_.y, q_.y, s); \
  p_ = cvt2hi(uu.y); q_ = cvt2hi(vv.y); s = fmaf(p_.x, q_.x, s); s = fmaf(p_.y, q_.y, s); \
  p_ = cvt2lo(uu.z); q_ = cvt2lo(vv.z); s = fmaf(p_.x, q_.x, s); s = fmaf(p_.y, q_.y, s); \
  p_ = cvt2hi(uu.z); q_ = cvt2hi(vv.z); s = fmaf(p_.x, q_.x, s); s = fmaf(p_.y, q_.y, s); \
  p_ = cvt2lo(uu.w); q_ = cvt2lo(vv.w); s = fmaf(p_.x, q_.x, s); s = fmaf(p_.y, q_.y, s); \
  p_ = cvt2hi(uu.w); q_ = cvt2hi(vv.w); s = fmaf(p_.x, q_.x, s); s = fmaf(p_.y, q_.y, s); }

__global__ __launch_bounds__(256) void loss_fp8(
    const u8* __restrict__ zf8, const int* __restrict__ ep,
    const int* __restrict__ en, int P, float* __restrict__ acc)
{
  __shared__ float red[8];
  const int tid = threadIdx.x;
  const int lane = tid & 63, wib = tid >> 6;
  const int sub = tid & 7;
  const int slot0 = blockIdx.x * 32 + (tid >> 3);
  const int step = gridDim.x * 32;
  float tp = 0.f, tn = 0.f;
  int g = slot0;
  for (; g + step < 2 * P; g += 2 * step) {
    const int gA = g, gB = g + step;
    const int negA = (gA >= P), negB = (gB >= P);
    const int pA = negA ? gA - P : gA, pB = negB ? gB - P : gB;
    const int* iA = negA ? en : ep;
    const int* iB = negB ? en : ep;
    const int naA = iA[pA], nbA = iA[P + pA];
    const int naB = iB[pB], nbB = iB[P + pB];
    const uint4 ra1 = *(const uint4*)(zf8 + (size_t)naA * 128 + sub * 16);
    const uint4 rb1 = *(const uint4*)(zf8 + (size_t)nbA * 128 + sub * 16);
    const uint4 ra2 = *(const uint4*)(zf8 + (size_t)naB * 128 + sub * 16);
    const uint4 rb2 = *(const uint4*)(zf8 + (size_t)nbB * 128 + sub * 16);
    float sA = 0.f, sB = 0.f;
    DOTV(ra1, rb1, sA)
    DOTV(ra2, rb2, sB)
#pragma unroll
    for (int off = 4; off; off >>= 1) {
      sA += __shfl_down(sA, off, 8);
      sB += __shfl_down(sB, off, 8);
    }
    if (sub == 0) {
      const float gA_ = 1.f / (1.f + expf(-sA));
      if (negA) tn += logf(1.f - gA_ + 1e-15f); else tp += logf(gA_ + 1e-15f);
      const float gB_ = 1.f / (1.f + expf(-sB));
      if (negB) tn += logf(1.f - gB_ + 1e-15f); else tp += logf(gB_ + 1e-15f);
    }
  }
  if (g < 2 * P) {
    const int neg = (g >= P);
    const int p = neg ? g - P : g;
    const int* ia = neg ? en : ep;
    const int na = ia[p], nb = ia[P + p];
    const uint4 ra = *(const uint4*)(zf8 + (size_t)na * 128 + sub * 16);
    const uint4 rb = *(const uint4*)(zf8 + (size_t)nb * 128 + sub * 16);
    float s = 0.f;
    DOTV(ra, rb, s)
#pragma unroll
    for (int off = 4; off; off >>= 1) s += __shfl_down(s, off, 8);
    if (sub == 0) {
      const float sig = 1.f / (1.f + expf(-s));
      if (neg) tn += logf(1.f - sig + 1e-15f); else tp += logf(sig + 1e-15f);
    }
  }
  tp += __shfl_down(tp, 32, 64); tn += __shfl_down(tn, 32, 64);
  tp += __shfl_down(tp, 16, 64); tn += __shfl_down(tn, 16, 64);
  tp += __shfl_down(tp, 8, 64);  tn += __shfl_down(tn, 8, 64);
  if (lane == 0) { red[wib] = tp; red[4 + wib] = tn; }
  __syncthreads();
  if (tid == 0) {
    atomicAdd(acc + 0, red[0] + red[1] + red[2] + red[3]);
    atomicAdd(acc + 1, red[4] + red[5] + red[6] + red[7]);
  }
}
#undef DOTV

// ---------------- fused gather2 + final (int2 CSR)
__global__ void gather2_final(
    const float* __restrict__ t1, const float* __restrict__ t0,
    const int* __restrict__ ptr, const int2* __restrict__ csr,
    const float* __restrict__ accs,
    const float* __restrict__ c1, const float* __restrict__ c2,
    float* __restrict__ out, int M, float invP)
{
  const int i = blockIdx.x * blockDim.x + threadIdx.x;
  if (i < M) {
    float a0 = 0.f, a1 = 0.f;
    const int beg = ptr[i], end = ptr[i + 1];
    int p = beg;
    for (; p + 4 <= end; p += 4) {
      const int2 e0 = csr[p], e1 = csr[p + 1], e2 = csr[p + 2], e3 = csr[p + 3];
      const float w0 = __int_as_float(e0.y), w1 = __int_as_float(e1.y);
      const float w2 = __int_as_float(e2.y), w3 = __int_as_float(e3.y);
      const float2 v0 = *(const float2*)(t1 + (size_t)e0.x * 2);
      const float2 v1 = *(const float2*)(t1 + (size_t)e1.x * 2);
      const float2 v2 = *(const float2*)(t1 + (size_t)e2.x * 2);
      const float2 v3 = *(const float2*)(t1 + (size_t)e3.x * 2);
      a0 = fmaf(w0, v0.x, a0); a1 = fmaf(w0, v0.y, a1);
      a0 = fmaf(w1, v1.x, a0); a1 = fmaf(w1, v1.y, a1);
      a0 = fmaf(w2, v2.x, a0); a1 = fmaf(w2, v2.y, a1);
      a0 = fmaf(w3, v3.x, a0); a1 = fmaf(w3, v3.y, a1);
    }
    for (; p < end; ++p) {
      const int2 eq = csr[p]; const float wq = __int_as_float(eq.y);
      const float2 v = *(const float2*)(t1 + (size_t)eq.x * 2);
      a0 = fmaf(wq, v.x, a0); a1 = fmaf(wq, v.y, a1);
    }
    const float2 base = *(const float2*)(t0 + (size_t)i * 2);
    *(float2*)(out + (size_t)i * 2) = make_float2(base.x + a0, base.y + a1);
  }
  if (i == 0) {
    out[2 * M + 0] = -(accs[0] + accs[1]) * invP;
    out[2 * M + 1] = c1[0];
    out[2 * M + 2] = c2[0];
  }
}

extern "C" void kernel_launch(void* const* d_in, const int* in_sizes, int n_in,
                              void* d_out, int out_size, void* d_ws, size_t ws_size,
                              hipStream_t stream)
{
  const float* x   = (const float*)d_in[0];
  const int*   ei  = (const int*)d_in[1];
  const int*   ep  = (const int*)d_in[2];
  const int*   en  = (const int*)d_in[3];
  const float* W1  = (const float*)d_in[4];
  const float* b1  = (const float*)d_in[5];
  const float* W2  = (const float*)d_in[6];
  const float* b2  = (const float*)d_in[7];
  const float* W3  = (const float*)d_in[8];
  const float* b3  = (const float*)d_in[9];
  const float* l1W = (const float*)d_in[10];
  const float* l1b = (const float*)d_in[11];
  const float* l2W = (const float*)d_in[12];
  const float* l2b = (const float*)d_in[13];
  const float* c1  = (const float*)d_in[14];
  const float* c2  = (const float*)d_in[15];
  float* out = (float*)d_out;

  const int M = in_sizes[0] / 128;  // 50000
  const int E = in_sizes[1] / 2;    // 800000
  const int P = in_sizes[2] / 2;    // 400000
  const int* src = ei;
  const int* dst = ei + E;
  const int nb_scan = (M + 255) / 256;

  float* ws = (float*)d_ws;
  size_t o = 0;
  float*    dinv = ws + o;            o += 50176;
  int*      cnt  = (int*)(ws + o);    o += (size_t)M;
  int*      ptr  = (int*)(ws + o);    o += (size_t)M + 8;
  int*      bsum = (int*)(ws + o);    o += 256;
  int2*     csr  = (int2*)(ws + o);   o += (size_t)E * 2;      // packed {src, wbits}
  ushort_t* rank = (ushort_t*)(ws + o); o += (size_t)E / 2;
  ushort_t* xb   = (ushort_t*)(ws + o); o += (size_t)M * 64;   // bf16 [M][128]
  u8*       xf8  = (u8*)(ws + o);     o += (size_t)M * 32;     // fp8 [M][128]
  ushort_t* tx0b = (ushort_t*)(ws + o); o += (size_t)M * 64;   // bf16 [M][128]
  ushort_t* W1t  = (ushort_t*)(ws + o); o += 40960;            // [320][256]
  ushort_t* W2t  = (ushort_t*)(ws + o); o += 35840;            // [224][320]
  ushort_t* Wlt  = (ushort_t*)(ws + o); o += 14336;            // [224][128]
  ushort_t* h    = (ushort_t*)(ws + o); o += (size_t)M * 160;  // bf16 [M][320], 32MB
  float*    Ar   = ws + o;            o += (size_t)M * 128;    // f32 stride128, 25.6MB
  u8*       Brh  = (u8*)(ws + o);     o += (size_t)M * 32;     // fp8 [M][128]
  u8*       zf8  = (u8*)(ws + o);     o += (size_t)M * 32;     // fp8 [M][128]
  float*    t0   = ws + o;            o += (size_t)M * 2;
  float*    t1   = ws + o;            o += (size_t)M * 2;
  float*    accs = ws + o;            o += 8;
  // partial tables alias regions dead during CSR build:
  unsigned* partS = (unsigned*)h;   // 256*25000*4 = 25.6MB <= 32MB (h written after fill)
  unsigned* partD = (unsigned*)Ar;  // 256*25000*4 = 25.6MB == Ar size (written after fill)

  hipMemsetAsync(accs, 0, 2 * 4, stream);
  hipMemsetAsync(Brh,  0, (size_t)M * 128, stream);  // pad cols must decode to 0
  hipMemsetAsync(zf8,  0, (size_t)M * 128, stream);

  // packing (independent, early)
  cvt_x_kernel<<<(M * 32 + 255) / 256, 256, 0, stream>>>(x, xb, xf8, M * 32);
  pack_all<<<(182272 + 255) / 256, 256, 0, stream>>>(W1, W2, l1W, l2W, W1t, W2t, Wlt);

  // CSR build (no global atomics)
  hist2<<<NB_H, 256, 0, stream>>>(src, dst, E, M, partS, partD, rank);
  reduce_base<<<(PW + 255) / 256, 256, 0, stream>>>(partS, partD, dinv, cnt, M);
  scan_local<<<nb_scan, 256, 0, stream>>>(cnt, ptr, bsum, M);
  scan_bsum<<<1, 256, 0, stream>>>(bsum, nb_scan);
  scan_add<<<nb_scan, 256, 0, stream>>>(ptr, bsum, M, E);
  fill_csr2<<<(E + 255) / 256, 256, 0, stream>>>(src, dst, dinv, ptr, partD, rank, csr, E);

  const int gB = (M + 63) / 64;
  const int gE8 = (M * 8 + 255) / 256;

  // conv1
  gather128e<<<gE8, 256, 0, stream>>>(xf8, tx0b, ptr, csr, M);
  gemm_mfma<0, 320, 256><<<gB, 256, 0, stream>>>(
      xb, tx0b, W1t, b1, nullptr, nullptr, nullptr, nullptr, h, nullptr, nullptr, nullptr, M);

  // conv2 (propagate after GEMM at 100)
  gemm_mfma<1, 224, 320><<<gB, 256, 0, stream>>>(
      h, nullptr, W2t, b2, nullptr, nullptr, nullptr, nullptr, Ar, Brh, nullptr, nullptr, M);
  gather100e_x1<<<gE8, 256, 0, stream>>>(Brh, Ar, ptr, csr, M);

  // lins + fused w3 (x2 never materialized)
  gemm_mfma<2, 224, 128><<<gB, 256, 0, stream>>>(
      xb, nullptr, Wlt, l1b, l2b, Ar /*x1*/, W3, b3, nullptr, zf8, t0, t1, M);

  // loss
  loss_fp8<<<2048, 256, 0, stream>>>(zf8, ep, en, P, accs);

  // conv3 propagation + final
  gather2_final<<<(M + 255) / 256, 256, 0, stream>>>(t1, t0, ptr, csr,
                                                     accs, c1, c2, out, M, 1.0f / (float)P);
}

// Round 10
// 481.523 us; speedup vs baseline: 1.1791x; 1.0047x over previous
//
#include <hip/hip_runtime.h>
#include <math.h>

// MTGCN R8: MLP push. loss 4-way pair ILP; gathers 8-edge unroll;
// reduce_base -> 8-thread cooperative (782 blocks, register-resident 32-entry
// prefix + 8-lane shuffle scan). CSR build stays atomic-free (R7 hist2 + rank).
// bf16 MFMA GEMMs; fp8 128B-line rows for all random-row reads; eighth-wave.

typedef unsigned short ushort_t;
typedef unsigned char u8;
typedef __attribute__((ext_vector_type(8))) __bf16 bf16x8;
typedef __attribute__((ext_vector_type(8))) short s16x8;
typedef __attribute__((ext_vector_type(4))) float f32x4;
typedef __attribute__((ext_vector_type(2))) float f32x2;

#define NB_H 256     // histogram blocks (1 per CU)
#define HW 12500     // LDS words per range (25000 bins packed 2/u32)
#define PW 25000     // packed words per block in partial tables

__device__ __forceinline__ f32x4 mfma16x16x32(s16x8 a, s16x8 b, f32x4 c) {
  return __builtin_amdgcn_mfma_f32_16x16x32_bf16(
      __builtin_bit_cast(bf16x8, a), __builtin_bit_cast(bf16x8, b), c, 0, 0, 0);
}
__device__ __forceinline__ ushort_t f2bf(float f) {
  union { float f; unsigned u; } c; c.f = f;
  unsigned r = (c.u + 0x7FFFu + ((c.u >> 16) & 1u)) >> 16;
  return (ushort_t)r;
}
__device__ __forceinline__ f32x2 cvt2lo(unsigned u) {
  return __builtin_amdgcn_cvt_pk_f32_fp8((int)u, false);
}
__device__ __forceinline__ f32x2 cvt2hi(unsigned u) {
  return __builtin_amdgcn_cvt_pk_f32_fp8((int)u, true);
}
__device__ __forceinline__ u8 f2fp8(float f) {
  return (u8)(__builtin_amdgcn_cvt_pk_fp8_f32(f, 0.f, 0, false) & 0xff);
}

// =======================================================================
// MFMA GEMM (unchanged from R7)
// =======================================================================
template<int VAR, int NT, int KTOT>
__global__ __launch_bounds__(256) void gemm_mfma(
    const ushort_t* __restrict__ A0, const ushort_t* __restrict__ A1,
    const ushort_t* __restrict__ Wt,
    const float* __restrict__ bias0, const float* __restrict__ bias1,
    const float* __restrict__ x1,
    const float* __restrict__ W3c, const float* __restrict__ b3c,
    void* __restrict__ out0, void* __restrict__ out1,
    float* __restrict__ t0g, float* __restrict__ t1g, int M)
{
  constexpr int NF = NT / 32;
  __shared__ __align__(16) ushort_t As[64 * 40];
  __shared__ __align__(16) ushort_t Bs[NT * 40];
  __shared__ float w3s[400];
  const int tid  = threadIdx.x;
  const int lane = tid & 63, w = tid >> 6;
  const int m0 = blockIdx.x * 64;
  const int wm = (w & 1) * 32, wn = (w >> 1) * (NT / 2);
  if (VAR == 2) { for (int i = tid; i < 400; i += 256) w3s[i] = W3c[i]; }
  f32x4 acc[2][NF];
#pragma unroll
  for (int i = 0; i < 2; ++i)
#pragma unroll
    for (int j = 0; j < NF; ++j) acc[i][j] = (f32x4){0.f, 0.f, 0.f, 0.f};

  for (int k0 = 0; k0 < KTOT; k0 += 32) {
    { // A stage
      const int r = tid >> 2, c8 = (tid & 3) * 8;
      const int gm = m0 + r;
      uint4 v = {0u, 0u, 0u, 0u};
      if (gm < M) {
        const ushort_t* srcp;
        if (VAR == 0) srcp = (k0 < 128) ? A0 + (size_t)gm * 128 + k0 + c8
                                        : A1 + (size_t)gm * 128 + (k0 - 128) + c8;
        else if (VAR == 1) srcp = A0 + (size_t)gm * 320 + k0 + c8;
        else srcp = A0 + (size_t)gm * 128 + k0 + c8;
        v = *(const uint4*)srcp;
      }
      *(uint4*)&As[r * 40 + c8] = v;
    }
    { // B stage
      const int c8 = (tid & 3) * 8;
#pragma unroll
      for (int i = 0; i < (NT * 4 + 255) / 256; ++i) {
        const int r = (tid >> 2) + i * 64;
        if (r < NT)
          *(uint4*)&Bs[r * 40 + c8] = *(const uint4*)(Wt + (size_t)r * KTOT + k0 + c8);
      }
    }
    __syncthreads();
    s16x8 af[2], bfr[NF];
#pragma unroll
    for (int mi = 0; mi < 2; ++mi)
      af[mi] = *(const s16x8*)&As[(wm + mi * 16 + (lane & 15)) * 40 + (lane >> 4) * 8];
#pragma unroll
    for (int ni = 0; ni < NF; ++ni)
      bfr[ni] = *(const s16x8*)&Bs[(wn + ni * 16 + (lane & 15)) * 40 + (lane >> 4) * 8];
#pragma unroll
    for (int mi = 0; mi < 2; ++mi)
#pragma unroll
      for (int ni = 0; ni < NF; ++ni)
        acc[mi][ni] = mfma16x16x32(af[mi], bfr[ni], acc[mi][ni]);
    __syncthreads();
  }

  if (VAR == 2) {
#pragma unroll
    for (int mi = 0; mi < 2; ++mi)
#pragma unroll
      for (int r = 0; r < 4; ++r) {
        const int gRow = m0 + wm + mi * 16 + ((lane >> 4) << 2) + r;
        float p0 = 0.f, p1 = 0.f, p2 = 0.f, p3 = 0.f;
#pragma unroll
        for (int ni = 0; ni < NF; ++ni) {
          const int col = wn + ni * 16 + (lane & 15);
          const float v = acc[mi][ni][r];
          if (gRow < M) {
            if (col < 100) {
              const float x2v = x1[(size_t)gRow * 128 + col] + fmaxf(v + bias0[col], 0.f);
              p0 = fmaf(x2v, w3s[col * 2 + 0], p0);
              p1 = fmaf(x2v, w3s[col * 2 + 1], p1);
              p2 = fmaf(x2v, w3s[200 + col * 2 + 0], p2);
              p3 = fmaf(x2v, w3s[200 + col * 2 + 1], p3);
            } else if (col < 200) {
              const int c = col - 100;
              ((u8*)out1)[(size_t)gRow * 128 + c] =
                  f2fp8(x1[(size_t)gRow * 128 + c] + fmaxf(v + bias1[c], 0.f));
            }
          }
        }
        if (wn == 0) {
#pragma unroll
          for (int off = 8; off; off >>= 1) {
            p0 += __shfl_down(p0, off, 16);
            p1 += __shfl_down(p1, off, 16);
            p2 += __shfl_down(p2, off, 16);
            p3 += __shfl_down(p3, off, 16);
          }
          if ((lane & 15) == 0 && gRow < M) {
            t0g[(size_t)gRow * 2 + 0] = p0 + b3c[0];
            t0g[(size_t)gRow * 2 + 1] = p1 + b3c[1];
            t1g[(size_t)gRow * 2 + 0] = p2;
            t1g[(size_t)gRow * 2 + 1] = p3;
          }
        }
      }
  } else {
#pragma unroll
    for (int mi = 0; mi < 2; ++mi)
#pragma unroll
      for (int ni = 0; ni < NF; ++ni)
#pragma unroll
        for (int r = 0; r < 4; ++r) {
          const int gRow = m0 + wm + mi * 16 + ((lane >> 4) << 2) + r;
          const int col  = wn + ni * 16 + (lane & 15);
          if (gRow >= M) continue;
          const float v = acc[mi][ni][r];
          if (VAR == 0) {
            ushort_t* h = (ushort_t*)out0;
            h[(size_t)gRow * 320 + col] = (col < 300) ? f2bf(fmaxf(v + bias0[col], 0.f))
                                                      : (ushort_t)0;
          } else {
            if (col < 100) ((float*)out0)[(size_t)gRow * 128 + col] = v + bias0[col];
            else if (col < 200) ((u8*)out1)[(size_t)gRow * 128 + (col - 100)] = f2fp8(v);
          }
        }
  }
}

// ---------------- packing / conversion ----------------
__global__ void cvt_x_kernel(const float* __restrict__ x, ushort_t* __restrict__ xb,
                             u8* __restrict__ xf8, int n4) {
  const int i = blockIdx.x * 256 + threadIdx.x;
  if (i < n4) {
    const float4 v = ((const float4*)x)[i];
    ushort4 o; o.x = f2bf(v.x); o.y = f2bf(v.y); o.z = f2bf(v.z); o.w = f2bf(v.w);
    ((ushort4*)xb)[i] = o;
    int p = 0;
    p = __builtin_amdgcn_cvt_pk_fp8_f32(v.x, v.y, p, false);
    p = __builtin_amdgcn_cvt_pk_fp8_f32(v.z, v.w, p, true);
    ((unsigned*)xf8)[i] = (unsigned)p;
  }
}
__global__ void pack_all(const float* __restrict__ W1, const float* __restrict__ W2,
                         const float* __restrict__ l1W, const float* __restrict__ l2W,
                         ushort_t* __restrict__ W1t, ushort_t* __restrict__ W2t,
                         ushort_t* __restrict__ Wlt) {
  const int i = blockIdx.x * 256 + threadIdx.x;
  if (i < 81920) {                       // W1t [320][256]
    const int n = i >> 8, k = i & 255;
    float v = 0.f;
    if (n < 300) v = (k < 128) ? W1[k * 300 + n] : W1[38400 + (k - 128) * 300 + n];
    W1t[i] = f2bf(v);
  } else if (i < 153600) {               // W2t [224][320]
    const int j = i - 81920;
    const int n = j / 320, k = j - n * 320;
    float v = 0.f;
    if (n < 200 && k < 300) v = W2[(n < 100 ? 0 : 30000) + k * 100 + (n % 100)];
    W2t[j] = f2bf(v);
  } else if (i < 182272) {               // Wlt [224][128]
    const int j = i - 153600;
    const int n = j >> 7, k = j & 127;
    float v = 0.f;
    if (n < 100) v = l1W[n * 128 + k];
    else if (n < 200) v = l2W[(n - 100) * 128 + k];
    Wlt[j] = f2bf(v);
  }
}

// ---------------- histogram + rank: 256 blocks, packed 2-per-u32 bins ----------------
__global__ __launch_bounds__(256) void hist2(
    const int* __restrict__ src, const int* __restrict__ dst, int E, int M,
    unsigned* __restrict__ partS, unsigned* __restrict__ partD,
    ushort_t* __restrict__ rank)
{
  __shared__ unsigned hist[HW];
  const int b = blockIdx.x;
  const int cs = (E + NB_H - 1) / NB_H;
  const int e0 = b * cs;
  const int e1 = (e0 + cs < E) ? e0 + cs : E;
  for (int isD = 0; isD < 2; ++isD) {
    const int* keys = isD ? dst : src;
    unsigned* part = isD ? partD : partS;
    for (int r = 0; r < 2; ++r) {
      const int klo = r * 2 * HW;   // node range [klo, klo+25000)
      for (int i = threadIdx.x; i < HW; i += 256) hist[i] = 0;
      __syncthreads();
      for (int e = e0 + threadIdx.x; e < e1; e += 256) {
        const int k = keys[e] - klo;
        if ((unsigned)k < (unsigned)(2 * HW)) {
          const unsigned old = atomicAdd(&hist[k >> 1], (k & 1) ? 0x10000u : 1u);
          if (isD) rank[e] = (ushort_t)((old >> ((k & 1) * 16)) & 0xffffu);
        }
      }
      __syncthreads();
      for (int i = threadIdx.x; i < HW; i += 256)
        part[(size_t)b * PW + r * HW + i] = hist[i];
      __syncthreads();
    }
  }
}

// ---------------- reduce_base8: 8 threads per packed pair (782 blocks).
// Thread t handles block segment [32t, 32t+32): registers hold the 32 partD
// entries; local exclusive prefix in regs; 8-lane shuffle scan combines.
// Packed u16-pair arithmetic (halves can't carry: counts < 65536).
__global__ __launch_bounds__(256) void reduce_base8(
    const unsigned* __restrict__ partS, unsigned* __restrict__ partD,
    float* __restrict__ dinv, int* __restrict__ cnt, int M)
{
  const int gtid = blockIdx.x * 256 + threadIdx.x;
  const int i = gtid >> 3;
  const int t = gtid & 7;
  if (i >= PW) return;
  const int b0 = t * 32;
  // out-degree segment sum
  unsigned ssum = 0;
#pragma unroll 8
  for (int b = 0; b < 32; ++b) ssum += partS[(size_t)(b0 + b) * PW + i];
#pragma unroll
  for (int off = 4; off; off >>= 1) ssum += __shfl_down(ssum, off, 8);
  // in-degree: register-resident local exclusive prefix
  unsigned vals[32];
#pragma unroll 8
  for (int b = 0; b < 32; ++b) vals[b] = partD[(size_t)(b0 + b) * PW + i];
  unsigned run = 0;
#pragma unroll
  for (int b = 0; b < 32; ++b) { const unsigned v = vals[b]; vals[b] = run; run += v; }
  // exclusive scan of segment totals across the 8 lanes
  unsigned inc = run;
#pragma unroll
  for (int off = 1; off < 8; off <<= 1) {
    const unsigned u = __shfl_up(inc, off, 8);
    if (t >= off) inc += u;
  }
  const unsigned excl = inc - run;
  const unsigned total = __shfl(inc, 7, 8);
#pragma unroll 8
  for (int b = 0; b < 32; ++b) partD[(size_t)(b0 + b) * PW + i] = vals[b] + excl;
  if (t == 0) {
    const int k = 2 * i;
    const unsigned s0 = ssum & 0xffffu, s1 = ssum >> 16;
    const unsigned d0 = total & 0xffffu, d1 = total >> 16;
    if (k < M) { dinv[k] = s0 ? 1.f / sqrtf((float)s0) : 0.f; cnt[k] = (int)d0; }
    if (k + 1 < M) { dinv[k + 1] = s1 ? 1.f / sqrtf((float)s1) : 0.f; cnt[k + 1] = (int)d1; }
  }
}

// ---------------- scan (unchanged)
__global__ void scan_local(const int* __restrict__ cnt, int* __restrict__ ptr,
                           int* __restrict__ bsum, int n)
{
  __shared__ int tmp[256];
  const int i = blockIdx.x * 256 + threadIdx.x;
  const int v = (i < n) ? cnt[i] : 0;
  tmp[threadIdx.x] = v;
  __syncthreads();
  for (int off = 1; off < 256; off <<= 1) {
    const int t = (threadIdx.x >= off) ? tmp[threadIdx.x - off] : 0;
    __syncthreads();
    tmp[threadIdx.x] += t;
    __syncthreads();
  }
  if (i < n) ptr[i] = tmp[threadIdx.x] - v;
  if (threadIdx.x == 255) bsum[blockIdx.x] = tmp[255];
}
__global__ void scan_bsum(int* __restrict__ bsum, int nb) {
  __shared__ int tmp[256];
  const int v = (threadIdx.x < nb) ? bsum[threadIdx.x] : 0;
  tmp[threadIdx.x] = v;
  __syncthreads();
  for (int off = 1; off < 256; off <<= 1) {
    const int t = (threadIdx.x >= off) ? tmp[threadIdx.x - off] : 0;
    __syncthreads();
    tmp[threadIdx.x] += t;
    __syncthreads();
  }
  if (threadIdx.x < nb) bsum[threadIdx.x] = tmp[threadIdx.x] - v;
}
__global__ void scan_add(int* __restrict__ ptr, const int* __restrict__ bsum, int n, int E) {
  const int i = blockIdx.x * 256 + threadIdx.x;
  if (i < n) ptr[i] += bsum[blockIdx.x];
  if (i == 0) ptr[n] = E;
}

// ---------------- atomic-free fill: pos = ptr[d] + base[b][d] + rank[e]
__global__ void fill_csr2(const int* __restrict__ src, const int* __restrict__ dst,
                          const float* __restrict__ dinv, const int* __restrict__ ptr,
                          const unsigned* __restrict__ base32,
                          const ushort_t* __restrict__ rank,
                          int2* __restrict__ csr, int E)
{
  const int e = blockIdx.x * 256 + threadIdx.x;
  if (e >= E) return;
  const int cs = (E + NB_H - 1) / NB_H;
  const int b = e / cs;
  const int s = src[e], d = dst[e];
  const unsigned bv = base32[(size_t)b * PW + (d >> 1)];
  const int base = (int)((bv >> ((d & 1) * 16)) & 0xffffu);
  const int pos = ptr[d] + base + (int)rank[e];
  const float w = -dinv[s] * dinv[d];
  csr[pos] = make_int2(s, __float_as_int(w));
}

// fp8 decode+accumulate: 16 fp8 (uint4) scaled by ww into a[0..15]
#define ACCV(u, ww) { f32x2 t; \
  t = cvt2lo(u.x); a[0]  = fmaf(ww, t.x, a[0]);  a[1]  = fmaf(ww, t.y, a[1]);  \
  t = cvt2hi(u.x); a[2]  = fmaf(ww, t.x, a[2]);  a[3]  = fmaf(ww, t.y, a[3]);  \
  t = cvt2lo(u.y); a[4]  = fmaf(ww, t.x, a[4]);  a[5]  = fmaf(ww, t.y, a[5]);  \
  t = cvt2hi(u.y); a[6]  = fmaf(ww, t.x, a[6]);  a[7]  = fmaf(ww, t.y, a[7]);  \
  t = cvt2lo(u.z); a[8]  = fmaf(ww, t.x, a[8]);  a[9]  = fmaf(ww, t.y, a[9]);  \
  t = cvt2hi(u.z); a[10] = fmaf(ww, t.x, a[10]); a[11] = fmaf(ww, t.y, a[11]); \
  t = cvt2lo(u.w); a[12] = fmaf(ww, t.x, a[12]); a[13] = fmaf(ww, t.y, a[13]); \
  t = cvt2hi(u.w); a[14] = fmaf(ww, t.x, a[14]); a[15] = fmaf(ww, t.y, a[15]); }

// ---------------- gather128: eighth-wave, 8-edge unroll, int2 CSR
__global__ __launch_bounds__(256) void gather128e(
    const u8* __restrict__ xf8, ushort_t* __restrict__ txb,
    const int* __restrict__ ptr, const int2* __restrict__ csr, int M)
{
  const int node = (blockIdx.x * 256 + threadIdx.x) >> 3;
  const int sub  = threadIdx.x & 7;
  if (node >= M) return;
  const int beg = ptr[node], end = ptr[node + 1];
  float a[16] = {};
  int p = beg;
  for (; p + 8 <= end; p += 8) {
    int2 e[8];
#pragma unroll
    for (int q = 0; q < 8; ++q) e[q] = csr[p + q];
    uint4 v[8];
#pragma unroll
    for (int q = 0; q < 8; ++q)
      v[q] = *(const uint4*)(xf8 + (size_t)e[q].x * 128 + sub * 16);
#pragma unroll
    for (int q = 0; q < 8; ++q) { const float wq = __int_as_float(e[q].y); ACCV(v[q], wq) }
  }
  for (; p < end; ++p) {
    const int2 eq = csr[p]; const float wq = __int_as_float(eq.y);
    const uint4 v = *(const uint4*)(xf8 + (size_t)eq.x * 128 + sub * 16);
    ACCV(v, wq)
  }
  uint4 o1, o2;
  o1.x = (unsigned)f2bf(a[0])  | ((unsigned)f2bf(a[1])  << 16);
  o1.y = (unsigned)f2bf(a[2])  | ((unsigned)f2bf(a[3])  << 16);
  o1.z = (unsigned)f2bf(a[4])  | ((unsigned)f2bf(a[5])  << 16);
  o1.w = (unsigned)f2bf(a[6])  | ((unsigned)f2bf(a[7])  << 16);
  o2.x = (unsigned)f2bf(a[8])  | ((unsigned)f2bf(a[9])  << 16);
  o2.y = (unsigned)f2bf(a[10]) | ((unsigned)f2bf(a[11]) << 16);
  o2.z = (unsigned)f2bf(a[12]) | ((unsigned)f2bf(a[13]) << 16);
  o2.w = (unsigned)f2bf(a[14]) | ((unsigned)f2bf(a[15]) << 16);
  ushort_t* dstp = txb + (size_t)node * 128 + sub * 16;
  *(uint4*)dstp = o1;
  *(uint4*)(dstp + 8) = o2;
}

// ---------------- fused gather100 + x1 (eighth-wave, 8-edge unroll)
__global__ __launch_bounds__(256) void gather100e_x1(
    const u8* __restrict__ Brh, float* __restrict__ Ar,
    const int* __restrict__ ptr, const int2* __restrict__ csr, int M)
{
  const int node = (blockIdx.x * 256 + threadIdx.x) >> 3;
  const int sub  = threadIdx.x & 7;
  if (node >= M) return;
  const int beg = ptr[node], end = ptr[node + 1];
  float a[16] = {};
  int p = beg;
  for (; p + 8 <= end; p += 8) {
    int2 e[8];
#pragma unroll
    for (int q = 0; q < 8; ++q) e[q] = csr[p + q];
    uint4 v[8];
#pragma unroll
    for (int q = 0; q < 8; ++q)
      v[q] = *(const uint4*)(Brh + (size_t)e[q].x * 128 + sub * 16);
#pragma unroll
    for (int q = 0; q < 8; ++q) { const float wq = __int_as_float(e[q].y); ACCV(v[q], wq) }
  }
  for (; p < end; ++p) {
    const int2 eq = csr[p]; const float wq = __int_as_float(eq.y);
    const uint4 v = *(const uint4*)(Brh + (size_t)eq.x * 128 + sub * 16);
    ACCV(v, wq)
  }
  float* dstp = Ar + (size_t)node * 128 + sub * 16;
#pragma unroll
  for (int q = 0; q < 4; ++q) {
    float4 b = *(const float4*)(dstp + q * 4);
    b.x = fmaxf(b.x + a[q * 4 + 0], 0.f);
    b.y = fmaxf(b.y + a[q * 4 + 1], 0.f);
    b.z = fmaxf(b.z + a[q * 4 + 2], 0.f);
    b.w = fmaxf(b.w + a[q * 4 + 3], 0.f);
    *(float4*)(dstp + q * 4) = b;
  }
}
#undef ACCV

// ---------------- loss: eighth-wave per pair, 4-way pair ILP
#define DOTV(uu, vv, s) { f32x2 p_, q_; \
  p_ = cvt2lo(uu.x); q_ = cvt2lo(vv.x); s = fmaf(p_.x, q_.x, s); s = fmaf(p_.y, q_.y, s); \
  p_ = cvt2hi(uu.x); q_ = cvt2hi(vv.x); s = fmaf(p_.x, q_.x, s); s = fmaf(p_.y, q_.y, s); \
  p_ = cvt2lo(uu.y); q_ = cvt2lo(vv.y); s = fmaf(p_.x, q_.x, s); s = fmaf(p_.y, q_.y, s); \
  p_ = cvt2hi(uu.y); q_ = cvt2hi(vv.y); s = fmaf(p_.x, q_.x, s); s = fmaf(p_.y, q_.y, s); \
  p_ = cvt2lo(uu.z); q_ = cvt2lo(vv.z); s = fmaf(p_.x, q_.x, s); s = fmaf(p_.y, q_.y, s); \
  p_ = cvt2hi(uu.z); q_ = cvt2hi(vv.z); s = fmaf(p_.x, q_.x, s); s = fmaf(p_.y, q_.y, s); \
  p_ = cvt2lo(uu.w); q_ = cvt2lo(vv.w); s = fmaf(p_.x, q_.x, s); s = fmaf(p_.y, q_.y, s); \
  p_ = cvt2hi(uu.w); q_ = cvt2hi(vv.w); s = fmaf(p_.x, q_.x, s); s = fmaf(p_.y, q_.y, s); }

__global__ __launch_bounds__(256) void loss_fp8(
    const u8* __restrict__ zf8, const int* __restrict__ ep,
    const int* __restrict__ en, int P, float* __restrict__ acc)
{
  __shared__ float red[8];
  const int tid = threadIdx.x;
  const int lane = tid & 63, wib = tid >> 6;
  const int sub = tid & 7;
  const int slot0 = blockIdx.x * 32 + (tid >> 3);
  const int step = gridDim.x * 32;
  float tp = 0.f, tn = 0.f;
  int g = slot0;
  for (; g + 3 * step < 2 * P; g += 4 * step) {
    int neg[4], na[4], nb[4];
#pragma unroll
    for (int q = 0; q < 4; ++q) {
      const int gq = g + q * step;
      neg[q] = (gq >= P);
      const int p = neg[q] ? gq - P : gq;
      const int* ia = neg[q] ? en : ep;
      na[q] = ia[p]; nb[q] = ia[P + p];
    }
    uint4 ra[4], rb[4];
#pragma unroll
    for (int q = 0; q < 4; ++q) {
      ra[q] = *(const uint4*)(zf8 + (size_t)na[q] * 128 + sub * 16);
      rb[q] = *(const uint4*)(zf8 + (size_t)nb[q] * 128 + sub * 16);
    }
    float s[4] = {0.f, 0.f, 0.f, 0.f};
#pragma unroll
    for (int q = 0; q < 4; ++q) DOTV(ra[q], rb[q], s[q])
#pragma unroll
    for (int off = 4; off; off >>= 1) {
#pragma unroll
      for (int q = 0; q < 4; ++q) s[q] += __shfl_down(s[q], off, 8);
    }
    if (sub == 0) {
#pragma unroll
      for (int q = 0; q < 4; ++q) {
        const float sig = 1.f / (1.f + expf(-s[q]));
        if (neg[q]) tn += logf(1.f - sig + 1e-15f); else tp += logf(sig + 1e-15f);
      }
    }
  }
  for (; g < 2 * P; g += step) {
    const int neg = (g >= P);
    const int p = neg ? g - P : g;
    const int* ia = neg ? en : ep;
    const int na = ia[p], nb = ia[P + p];
    const uint4 ra = *(const uint4*)(zf8 + (size_t)na * 128 + sub * 16);
    const uint4 rb = *(const uint4*)(zf8 + (size_t)nb * 128 + sub * 16);
    float s = 0.f;
    DOTV(ra, rb, s)
#pragma unroll
    for (int off = 4; off; off >>= 1) s += __shfl_down(s, off, 8);
    if (sub == 0) {
      const float sig = 1.f / (1.f + expf(-s));
      if (neg) tn += logf(1.f - sig + 1e-15f); else tp += logf(sig + 1e-15f);
    }
  }
  tp += __shfl_down(tp, 32, 64); tn += __shfl_down(tn, 32, 64);
  tp += __shfl_down(tp, 16, 64); tn += __shfl_down(tn, 16, 64);
  tp += __shfl_down(tp, 8, 64);  tn += __shfl_down(tn, 8, 64);
  if (lane == 0) { red[wib] = tp; red[4 + wib] = tn; }
  __syncthreads();
  if (tid == 0) {
    atomicAdd(acc + 0, red[0] + red[1] + red[2] + red[3]);
    atomicAdd(acc + 1, red[4] + red[5] + red[6] + red[7]);
  }
}
#undef DOTV

// ---------------- fused gather2 + final (int2 CSR)
__global__ void gather2_final(
    const float* __restrict__ t1, const float* __restrict__ t0,
    const int* __restrict__ ptr, const int2* __restrict__ csr,
    const float* __restrict__ accs,
    const float* __restrict__ c1, const float* __restrict__ c2,
    float* __restrict__ out, int M, float invP)
{
  const int i = blockIdx.x * blockDim.x + threadIdx.x;
  if (i < M) {
    float a0 = 0.f, a1 = 0.f;
    const int beg = ptr[i], end = ptr[i + 1];
    int p = beg;
    for (; p + 4 <= end; p += 4) {
      const int2 e0 = csr[p], e1 = csr[p + 1], e2 = csr[p + 2], e3 = csr[p + 3];
      const float w0 = __int_as_float(e0.y), w1 = __int_as_float(e1.y);
      const float w2 = __int_as_float(e2.y), w3 = __int_as_float(e3.y);
      const float2 v0 = *(const float2*)(t1 + (size_t)e0.x * 2);
      const float2 v1 = *(const float2*)(t1 + (size_t)e1.x * 2);
      const float2 v2 = *(const float2*)(t1 + (size_t)e2.x * 2);
      const float2 v3 = *(const float2*)(t1 + (size_t)e3.x * 2);
      a0 = fmaf(w0, v0.x, a0); a1 = fmaf(w0, v0.y, a1);
      a0 = fmaf(w1, v1.x, a0); a1 = fmaf(w1, v1.y, a1);
      a0 = fmaf(w2, v2.x, a0); a1 = fmaf(w2, v2.y, a1);
      a0 = fmaf(w3, v3.x, a0); a1 = fmaf(w3, v3.y, a1);
    }
    for (; p < end; ++p) {
      const int2 eq = csr[p]; const float wq = __int_as_float(eq.y);
      const float2 v = *(const float2*)(t1 + (size_t)eq.x * 2);
      a0 = fmaf(wq, v.x, a0); a1 = fmaf(wq, v.y, a1);
    }
    const float2 base = *(const float2*)(t0 + (size_t)i * 2);
    *(float2*)(out + (size_t)i * 2) = make_float2(base.x + a0, base.y + a1);
  }
  if (i == 0) {
    out[2 * M + 0] = -(accs[0] + accs[1]) * invP;
    out[2 * M + 1] = c1[0];
    out[2 * M + 2] = c2[0];
  }
}

extern "C" void kernel_launch(void* const* d_in, const int* in_sizes, int n_in,
                              void* d_out, int out_size, void* d_ws, size_t ws_size,
                              hipStream_t stream)
{
  const float* x   = (const float*)d_in[0];
  const int*   ei  = (const int*)d_in[1];
  const int*   ep  = (const int*)d_in[2];
  const int*   en  = (const int*)d_in[3];
  const float* W1  = (const float*)d_in[4];
  const float* b1  = (const float*)d_in[5];
  const float* W2  = (const float*)d_in[6];
  const float* b2  = (const float*)d_in[7];
  const float* W3  = (const float*)d_in[8];
  const float* b3  = (const float*)d_in[9];
  const float* l1W = (const float*)d_in[10];
  const float* l1b = (const float*)d_in[11];
  const float* l2W = (const float*)d_in[12];
  const float* l2b = (const float*)d_in[13];
  const float* c1  = (const float*)d_in[14];
  const float* c2  = (const float*)d_in[15];
  float* out = (float*)d_out;

  const int M = in_sizes[0] / 128;  // 50000
  const int E = in_sizes[1] / 2;    // 800000
  const int P = in_sizes[2] / 2;    // 400000
  const int* src = ei;
  const int* dst = ei + E;
  const int nb_scan = (M + 255) / 256;

  float* ws = (float*)d_ws;
  size_t o = 0;
  float*    dinv = ws + o;            o += 50176;
  int*      cnt  = (int*)(ws + o);    o += (size_t)M;
  int*      ptr  = (int*)(ws + o);    o += (size_t)M + 8;
  int*      bsum = (int*)(ws + o);    o += 256;
  int2*     csr  = (int2*)(ws + o);   o += (size_t)E * 2;      // packed {src, wbits}
  ushort_t* rank = (ushort_t*)(ws + o); o += (size_t)E / 2;
  ushort_t* xb   = (ushort_t*)(ws + o); o += (size_t)M * 64;   // bf16 [M][128]
  u8*       xf8  = (u8*)(ws + o);     o += (size_t)M * 32;     // fp8 [M][128]
  ushort_t* tx0b = (ushort_t*)(ws + o); o += (size_t)M * 64;   // bf16 [M][128]
  ushort_t* W1t  = (ushort_t*)(ws + o); o += 40960;            // [320][256]
  ushort_t* W2t  = (ushort_t*)(ws + o); o += 35840;            // [224][320]
  ushort_t* Wlt  = (ushort_t*)(ws + o); o += 14336;            // [224][128]
  ushort_t* h    = (ushort_t*)(ws + o); o += (size_t)M * 160;  // bf16 [M][320], 32MB
  float*    Ar   = ws + o;            o += (size_t)M * 128;    // f32 stride128, 25.6MB
  u8*       Brh  = (u8*)(ws + o);     o += (size_t)M * 32;     // fp8 [M][128]
  u8*       zf8  = (u8*)(ws + o);     o += (size_t)M * 32;     // fp8 [M][128]
  float*    t0   = ws + o;            o += (size_t)M * 2;
  float*    t1   = ws + o;            o += (size_t)M * 2;
  float*    accs = ws + o;            o += 8;
  // partial tables alias regions dead during CSR build:
  unsigned* partS = (unsigned*)h;   // 25.6MB <= 32MB (h written after fill)
  unsigned* partD = (unsigned*)Ar;  // 25.6MB == Ar size (written after fill)

  hipMemsetAsync(accs, 0, 2 * 4, stream);
  hipMemsetAsync(Brh,  0, (size_t)M * 128, stream);  // pad cols must decode to 0
  hipMemsetAsync(zf8,  0, (size_t)M * 128, stream);

  // packing (independent, early)
  cvt_x_kernel<<<(M * 32 + 255) / 256, 256, 0, stream>>>(x, xb, xf8, M * 32);
  pack_all<<<(182272 + 255) / 256, 256, 0, stream>>>(W1, W2, l1W, l2W, W1t, W2t, Wlt);

  // CSR build (no global atomics)
  hist2<<<NB_H, 256, 0, stream>>>(src, dst, E, M, partS, partD, rank);
  reduce_base8<<<(PW * 8 + 255) / 256, 256, 0, stream>>>(partS, partD, dinv, cnt, M);
  scan_local<<<nb_scan, 256, 0, stream>>>(cnt, ptr, bsum, M);
  scan_bsum<<<1, 256, 0, stream>>>(bsum, nb_scan);
  scan_add<<<nb_scan, 256, 0, stream>>>(ptr, bsum, M, E);
  fill_csr2<<<(E + 255) / 256, 256, 0, stream>>>(src, dst, dinv, ptr, partD, rank, csr, E);

  const int gB = (M + 63) / 64;
  const int gE8 = (M * 8 + 255) / 256;

  // conv1
  gather128e<<<gE8, 256, 0, stream>>>(xf8, tx0b, ptr, csr, M);
  gemm_mfma<0, 320, 256><<<gB, 256, 0, stream>>>(
      xb, tx0b, W1t, b1, nullptr, nullptr, nullptr, nullptr, h, nullptr, nullptr, nullptr, M);

  // conv2 (propagate after GEMM at 100)
  gemm_mfma<1, 224, 320><<<gB, 256, 0, stream>>>(
      h, nullptr, W2t, b2, nullptr, nullptr, nullptr, nullptr, Ar, Brh, nullptr, nullptr, M);
  gather100e_x1<<<gE8, 256, 0, stream>>>(Brh, Ar, ptr, csr, M);

  // lins + fused w3 (x2 never materialized)
  gemm_mfma<2, 224, 128><<<gB, 256, 0, stream>>>(
      xb, nullptr, Wlt, l1b, l2b, Ar /*x1*/, W3, b3, nullptr, zf8, t0, t1, M);

  // loss
  loss_fp8<<<2048, 256, 0, stream>>>(zf8, ep, en, P, accs);

  // conv3 propagation + final
  gather2_final<<<(M + 255) / 256, 256, 0, stream>>>(t1, t0, ptr, csr,
                                                     accs, c1, c2, out, M, 1.0f / (float)P);
}

// Round 11
// 476.853 us; speedup vs baseline: 1.1906x; 1.0098x over previous
//
#include <hip/hip_runtime.h>
#include <math.h>

// MTGCN R9: fix reduce_base (split-role coalesced, register-resident unroll-8 —
// R8's version scratch-spilled vals[32] and had 8-way uncoalesced lanes);
// drop all memsets (garbage containment proven; loss masks pad bytes on both
// operands); zero accs in scan_bsum; fuse cvt_x into pack_all. 20 -> 14 dispatches.
// Rest as R8: atomic-free CSR (hist2+rank), bf16 MFMA GEMMs, fp8 128B-line rows.

typedef unsigned short ushort_t;
typedef unsigned char u8;
typedef __attribute__((ext_vector_type(8))) __bf16 bf16x8;
typedef __attribute__((ext_vector_type(8))) short s16x8;
typedef __attribute__((ext_vector_type(4))) float f32x4;
typedef __attribute__((ext_vector_type(2))) float f32x2;

#define NB_H 256     // histogram blocks (1 per CU)
#define HW 12500     // LDS words per range (25000 bins packed 2/u32)
#define PW 25000     // packed words per block in partial tables

__device__ __forceinline__ f32x4 mfma16x16x32(s16x8 a, s16x8 b, f32x4 c) {
  return __builtin_amdgcn_mfma_f32_16x16x32_bf16(
      __builtin_bit_cast(bf16x8, a), __builtin_bit_cast(bf16x8, b), c, 0, 0, 0);
}
__device__ __forceinline__ ushort_t f2bf(float f) {
  union { float f; unsigned u; } c; c.f = f;
  unsigned r = (c.u + 0x7FFFu + ((c.u >> 16) & 1u)) >> 16;
  return (ushort_t)r;
}
__device__ __forceinline__ f32x2 cvt2lo(unsigned u) {
  return __builtin_amdgcn_cvt_pk_f32_fp8((int)u, false);
}
__device__ __forceinline__ f32x2 cvt2hi(unsigned u) {
  return __builtin_amdgcn_cvt_pk_f32_fp8((int)u, true);
}
__device__ __forceinline__ u8 f2fp8(float f) {
  return (u8)(__builtin_amdgcn_cvt_pk_fp8_f32(f, 0.f, 0, false) & 0xff);
}

// =======================================================================
// MFMA GEMM (unchanged from R7/R8)
// =======================================================================
template<int VAR, int NT, int KTOT>
__global__ __launch_bounds__(256) void gemm_mfma(
    const ushort_t* __restrict__ A0, const ushort_t* __restrict__ A1,
    const ushort_t* __restrict__ Wt,
    const float* __restrict__ bias0, const float* __restrict__ bias1,
    const float* __restrict__ x1,
    const float* __restrict__ W3c, const float* __restrict__ b3c,
    void* __restrict__ out0, void* __restrict__ out1,
    float* __restrict__ t0g, float* __restrict__ t1g, int M)
{
  constexpr int NF = NT / 32;
  __shared__ __align__(16) ushort_t As[64 * 40];
  __shared__ __align__(16) ushort_t Bs[NT * 40];
  __shared__ float w3s[400];
  const int tid  = threadIdx.x;
  const int lane = tid & 63, w = tid >> 6;
  const int m0 = blockIdx.x * 64;
  const int wm = (w & 1) * 32, wn = (w >> 1) * (NT / 2);
  if (VAR == 2) { for (int i = tid; i < 400; i += 256) w3s[i] = W3c[i]; }
  f32x4 acc[2][NF];
#pragma unroll
  for (int i = 0; i < 2; ++i)
#pragma unroll
    for (int j = 0; j < NF; ++j) acc[i][j] = (f32x4){0.f, 0.f, 0.f, 0.f};

  for (int k0 = 0; k0 < KTOT; k0 += 32) {
    { // A stage
      const int r = tid >> 2, c8 = (tid & 3) * 8;
      const int gm = m0 + r;
      uint4 v = {0u, 0u, 0u, 0u};
      if (gm < M) {
        const ushort_t* srcp;
        if (VAR == 0) srcp = (k0 < 128) ? A0 + (size_t)gm * 128 + k0 + c8
                                        : A1 + (size_t)gm * 128 + (k0 - 128) + c8;
        else if (VAR == 1) srcp = A0 + (size_t)gm * 320 + k0 + c8;
        else srcp = A0 + (size_t)gm * 128 + k0 + c8;
        v = *(const uint4*)srcp;
      }
      *(uint4*)&As[r * 40 + c8] = v;
    }
    { // B stage
      const int c8 = (tid & 3) * 8;
#pragma unroll
      for (int i = 0; i < (NT * 4 + 255) / 256; ++i) {
        const int r = (tid >> 2) + i * 64;
        if (r < NT)
          *(uint4*)&Bs[r * 40 + c8] = *(const uint4*)(Wt + (size_t)r * KTOT + k0 + c8);
      }
    }
    __syncthreads();
    s16x8 af[2], bfr[NF];
#pragma unroll
    for (int mi = 0; mi < 2; ++mi)
      af[mi] = *(const s16x8*)&As[(wm + mi * 16 + (lane & 15)) * 40 + (lane >> 4) * 8];
#pragma unroll
    for (int ni = 0; ni < NF; ++ni)
      bfr[ni] = *(const s16x8*)&Bs[(wn + ni * 16 + (lane & 15)) * 40 + (lane >> 4) * 8];
#pragma unroll
    for (int mi = 0; mi < 2; ++mi)
#pragma unroll
      for (int ni = 0; ni < NF; ++ni)
        acc[mi][ni] = mfma16x16x32(af[mi], bfr[ni], acc[mi][ni]);
    __syncthreads();
  }

  if (VAR == 2) {
#pragma unroll
    for (int mi = 0; mi < 2; ++mi)
#pragma unroll
      for (int r = 0; r < 4; ++r) {
        const int gRow = m0 + wm + mi * 16 + ((lane >> 4) << 2) + r;
        float p0 = 0.f, p1 = 0.f, p2 = 0.f, p3 = 0.f;
#pragma unroll
        for (int ni = 0; ni < NF; ++ni) {
          const int col = wn + ni * 16 + (lane & 15);
          const float v = acc[mi][ni][r];
          if (gRow < M) {
            if (col < 100) {
              const float x2v = x1[(size_t)gRow * 128 + col] + fmaxf(v + bias0[col], 0.f);
              p0 = fmaf(x2v, w3s[col * 2 + 0], p0);
              p1 = fmaf(x2v, w3s[col * 2 + 1], p1);
              p2 = fmaf(x2v, w3s[200 + col * 2 + 0], p2);
              p3 = fmaf(x2v, w3s[200 + col * 2 + 1], p3);
            } else if (col < 200) {
              const int c = col - 100;
              ((u8*)out1)[(size_t)gRow * 128 + c] =
                  f2fp8(x1[(size_t)gRow * 128 + c] + fmaxf(v + bias1[c], 0.f));
            }
          }
        }
        if (wn == 0) {
#pragma unroll
          for (int off = 8; off; off >>= 1) {
            p0 += __shfl_down(p0, off, 16);
            p1 += __shfl_down(p1, off, 16);
            p2 += __shfl_down(p2, off, 16);
            p3 += __shfl_down(p3, off, 16);
          }
          if ((lane & 15) == 0 && gRow < M) {
            t0g[(size_t)gRow * 2 + 0] = p0 + b3c[0];
            t0g[(size_t)gRow * 2 + 1] = p1 + b3c[1];
            t1g[(size_t)gRow * 2 + 0] = p2;
            t1g[(size_t)gRow * 2 + 1] = p3;
          }
        }
      }
  } else {
#pragma unroll
    for (int mi = 0; mi < 2; ++mi)
#pragma unroll
      for (int ni = 0; ni < NF; ++ni)
#pragma unroll
        for (int r = 0; r < 4; ++r) {
          const int gRow = m0 + wm + mi * 16 + ((lane >> 4) << 2) + r;
          const int col  = wn + ni * 16 + (lane & 15);
          if (gRow >= M) continue;
          const float v = acc[mi][ni][r];
          if (VAR == 0) {
            ushort_t* h = (ushort_t*)out0;
            h[(size_t)gRow * 320 + col] = (col < 300) ? f2bf(fmaxf(v + bias0[col], 0.f))
                                                      : (ushort_t)0;
          } else {
            if (col < 100) ((float*)out0)[(size_t)gRow * 128 + col] = v + bias0[col];
            else if (col < 200) ((u8*)out1)[(size_t)gRow * 128 + (col - 100)] = f2fp8(v);
          }
        }
  }
}

// ---------------- fused conversion + weight packing (one kernel) ----------------
__global__ void pack_cvt(const float* __restrict__ x, ushort_t* __restrict__ xb,
                         u8* __restrict__ xf8, int n4,
                         const float* __restrict__ W1, const float* __restrict__ W2,
                         const float* __restrict__ l1W, const float* __restrict__ l2W,
                         ushort_t* __restrict__ W1t, ushort_t* __restrict__ W2t,
                         ushort_t* __restrict__ Wlt) {
  const int i = blockIdx.x * 256 + threadIdx.x;
  if (i < n4) {
    const float4 v = ((const float4*)x)[i];
    ushort4 o; o.x = f2bf(v.x); o.y = f2bf(v.y); o.z = f2bf(v.z); o.w = f2bf(v.w);
    ((ushort4*)xb)[i] = o;
    int p = 0;
    p = __builtin_amdgcn_cvt_pk_fp8_f32(v.x, v.y, p, false);
    p = __builtin_amdgcn_cvt_pk_fp8_f32(v.z, v.w, p, true);
    ((unsigned*)xf8)[i] = (unsigned)p;
    return;
  }
  const int j = i - n4;
  if (j < 81920) {                       // W1t [320][256]
    const int n = j >> 8, k = j & 255;
    float v = 0.f;
    if (n < 300) v = (k < 128) ? W1[k * 300 + n] : W1[38400 + (k - 128) * 300 + n];
    W1t[j] = f2bf(v);
  } else if (j < 153600) {               // W2t [224][320]
    const int jj = j - 81920;
    const int n = jj / 320, k = jj - n * 320;
    float v = 0.f;
    if (n < 200 && k < 300) v = W2[(n < 100 ? 0 : 30000) + k * 100 + (n % 100)];
    W2t[jj] = f2bf(v);
  } else if (j < 182272) {               // Wlt [224][128]
    const int jj = j - 153600;
    const int n = jj >> 7, k = jj & 127;
    float v = 0.f;
    if (n < 100) v = l1W[n * 128 + k];
    else if (n < 200) v = l2W[(n - 100) * 128 + k];
    Wlt[jj] = f2bf(v);
  }
}

// ---------------- histogram + rank: 256 blocks, packed 2-per-u32 bins ----------------
__global__ __launch_bounds__(256) void hist2(
    const int* __restrict__ src, const int* __restrict__ dst, int E, int M,
    unsigned* __restrict__ partS, unsigned* __restrict__ partD,
    ushort_t* __restrict__ rank)
{
  __shared__ unsigned hist[HW];
  const int b = blockIdx.x;
  const int cs = (E + NB_H - 1) / NB_H;
  const int e0 = b * cs;
  const int e1 = (e0 + cs < E) ? e0 + cs : E;
  for (int isD = 0; isD < 2; ++isD) {
    const int* keys = isD ? dst : src;
    unsigned* part = isD ? partD : partS;
    for (int r = 0; r < 2; ++r) {
      const int klo = r * 2 * HW;   // node range [klo, klo+25000)
      for (int i = threadIdx.x; i < HW; i += 256) hist[i] = 0;
      __syncthreads();
      for (int e = e0 + threadIdx.x; e < e1; e += 256) {
        const int k = keys[e] - klo;
        if ((unsigned)k < (unsigned)(2 * HW)) {
          const unsigned old = atomicAdd(&hist[k >> 1], (k & 1) ? 0x10000u : 1u);
          if (isD) rank[e] = (ushort_t)((old >> ((k & 1) * 16)) & 0xffffu);
        }
      }
      __syncthreads();
      for (int i = threadIdx.x; i < HW; i += 256)
        part[(size_t)b * PW + r * HW + i] = hist[i];
      __syncthreads();
    }
  }
}

// ---------------- reduce_base2: split-role, coalesced, register-resident unroll-8.
// t < PW: sum partS over 256 blocks -> dinv. t in [PW, 2PW): exclusive scan of
// partD over blocks (in place, packed u16 pairs) -> base table + cnt.
__global__ __launch_bounds__(256) void reduce_base2(
    const unsigned* __restrict__ partS, unsigned* __restrict__ partD,
    float* __restrict__ dinv, int* __restrict__ cnt, int M)
{
  const int t = blockIdx.x * 256 + threadIdx.x;
  if (t < PW) {
    const int i = t;
    unsigned ssum = 0;
    for (int b = 0; b < NB_H; b += 8) {
      unsigned v[8];
#pragma unroll
      for (int q = 0; q < 8; ++q) v[q] = partS[(size_t)(b + q) * PW + i];
#pragma unroll
      for (int q = 0; q < 8; ++q) ssum += v[q];
    }
    const int k = 2 * i;
    const unsigned s0 = ssum & 0xffffu, s1 = ssum >> 16;
    if (k < M) dinv[k] = s0 ? 1.f / sqrtf((float)s0) : 0.f;
    if (k + 1 < M) dinv[k + 1] = s1 ? 1.f / sqrtf((float)s1) : 0.f;
  } else if (t < 2 * PW) {
    const int i = t - PW;
    unsigned run = 0;
    for (int b = 0; b < NB_H; b += 8) {
      unsigned v[8], pre[8];
#pragma unroll
      for (int q = 0; q < 8; ++q) v[q] = partD[(size_t)(b + q) * PW + i];
#pragma unroll
      for (int q = 0; q < 8; ++q) { pre[q] = run; run += v[q]; }
#pragma unroll
      for (int q = 0; q < 8; ++q) partD[(size_t)(b + q) * PW + i] = pre[q];
    }
    const int k = 2 * i;
    if (k < M) cnt[k] = (int)(run & 0xffffu);
    if (k + 1 < M) cnt[k + 1] = (int)(run >> 16);
  }
}

// ---------------- scan
__global__ void scan_local(const int* __restrict__ cnt, int* __restrict__ ptr,
                           int* __restrict__ bsum, int n)
{
  __shared__ int tmp[256];
  const int i = blockIdx.x * 256 + threadIdx.x;
  const int v = (i < n) ? cnt[i] : 0;
  tmp[threadIdx.x] = v;
  __syncthreads();
  for (int off = 1; off < 256; off <<= 1) {
    const int t = (threadIdx.x >= off) ? tmp[threadIdx.x - off] : 0;
    __syncthreads();
    tmp[threadIdx.x] += t;
    __syncthreads();
  }
  if (i < n) ptr[i] = tmp[threadIdx.x] - v;
  if (threadIdx.x == 255) bsum[blockIdx.x] = tmp[255];
}
__global__ void scan_bsum(int* __restrict__ bsum, int nb, float* __restrict__ accs) {
  __shared__ int tmp[256];
  if (threadIdx.x < 2) accs[threadIdx.x] = 0.f;   // zero loss accumulators here
  const int v = (threadIdx.x < nb) ? bsum[threadIdx.x] : 0;
  tmp[threadIdx.x] = v;
  __syncthreads();
  for (int off = 1; off < 256; off <<= 1) {
    const int t = (threadIdx.x >= off) ? tmp[threadIdx.x - off] : 0;
    __syncthreads();
    tmp[threadIdx.x] += t;
    __syncthreads();
  }
  if (threadIdx.x < nb) bsum[threadIdx.x] = tmp[threadIdx.x] - v;
}
__global__ void scan_add(int* __restrict__ ptr, const int* __restrict__ bsum, int n, int E) {
  const int i = blockIdx.x * 256 + threadIdx.x;
  if (i < n) ptr[i] += bsum[blockIdx.x];
  if (i == 0) ptr[n] = E;
}

// ---------------- atomic-free fill: pos = ptr[d] + base[b][d] + rank[e]
__global__ void fill_csr2(const int* __restrict__ src, const int* __restrict__ dst,
                          const float* __restrict__ dinv, const int* __restrict__ ptr,
                          const unsigned* __restrict__ base32,
                          const ushort_t* __restrict__ rank,
                          int2* __restrict__ csr, int E)
{
  const int e = blockIdx.x * 256 + threadIdx.x;
  if (e >= E) return;
  const int cs = (E + NB_H - 1) / NB_H;
  const int b = e / cs;
  const int s = src[e], d = dst[e];
  const unsigned bv = base32[(size_t)b * PW + (d >> 1)];
  const int base = (int)((bv >> ((d & 1) * 16)) & 0xffffu);
  const int pos = ptr[d] + base + (int)rank[e];
  const float w = -dinv[s] * dinv[d];
  csr[pos] = make_int2(s, __float_as_int(w));
}

// fp8 decode+accumulate: 16 fp8 (uint4) scaled by ww into a[0..15]
#define ACCV(u, ww) { f32x2 t; \
  t = cvt2lo(u.x); a[0]  = fmaf(ww, t.x, a[0]);  a[1]  = fmaf(ww, t.y, a[1]);  \
  t = cvt2hi(u.x); a[2]  = fmaf(ww, t.x, a[2]);  a[3]  = fmaf(ww, t.y, a[3]);  \
  t = cvt2lo(u.y); a[4]  = fmaf(ww, t.x, a[4]);  a[5]  = fmaf(ww, t.y, a[5]);  \
  t = cvt2hi(u.y); a[6]  = fmaf(ww, t.x, a[6]);  a[7]  = fmaf(ww, t.y, a[7]);  \
  t = cvt2lo(u.z); a[8]  = fmaf(ww, t.x, a[8]);  a[9]  = fmaf(ww, t.y, a[9]);  \
  t = cvt2hi(u.z); a[10] = fmaf(ww, t.x, a[10]); a[11] = fmaf(ww, t.y, a[11]); \
  t = cvt2lo(u.w); a[12] = fmaf(ww, t.x, a[12]); a[13] = fmaf(ww, t.y, a[13]); \
  t = cvt2hi(u.w); a[14] = fmaf(ww, t.x, a[14]); a[15] = fmaf(ww, t.y, a[15]); }

// ---------------- gather128: eighth-wave, 8-edge unroll, int2 CSR
__global__ __launch_bounds__(256) void gather128e(
    const u8* __restrict__ xf8, ushort_t* __restrict__ txb,
    const int* __restrict__ ptr, const int2* __restrict__ csr, int M)
{
  const int node = (blockIdx.x * 256 + threadIdx.x) >> 3;
  const int sub  = threadIdx.x & 7;
  if (node >= M) return;
  const int beg = ptr[node], end = ptr[node + 1];
  float a[16] = {};
  int p = beg;
  for (; p + 8 <= end; p += 8) {
    int2 e[8];
#pragma unroll
    for (int q = 0; q < 8; ++q) e[q] = csr[p + q];
    uint4 v[8];
#pragma unroll
    for (int q = 0; q < 8; ++q)
      v[q] = *(const uint4*)(xf8 + (size_t)e[q].x * 128 + sub * 16);
#pragma unroll
    for (int q = 0; q < 8; ++q) { const float wq = __int_as_float(e[q].y); ACCV(v[q], wq) }
  }
  for (; p < end; ++p) {
    const int2 eq = csr[p]; const float wq = __int_as_float(eq.y);
    const uint4 v = *(const uint4*)(xf8 + (size_t)eq.x * 128 + sub * 16);
    ACCV(v, wq)
  }
  uint4 o1, o2;
  o1.x = (unsigned)f2bf(a[0])  | ((unsigned)f2bf(a[1])  << 16);
  o1.y = (unsigned)f2bf(a[2])  | ((unsigned)f2bf(a[3])  << 16);
  o1.z = (unsigned)f2bf(a[4])  | ((unsigned)f2bf(a[5])  << 16);
  o1.w = (unsigned)f2bf(a[6])  | ((unsigned)f2bf(a[7])  << 16);
  o2.x = (unsigned)f2bf(a[8])  | ((unsigned)f2bf(a[9])  << 16);
  o2.y = (unsigned)f2bf(a[10]) | ((unsigned)f2bf(a[11]) << 16);
  o2.z = (unsigned)f2bf(a[12]) | ((unsigned)f2bf(a[13]) << 16);
  o2.w = (unsigned)f2bf(a[14]) | ((unsigned)f2bf(a[15]) << 16);
  ushort_t* dstp = txb + (size_t)node * 128 + sub * 16;
  *(uint4*)dstp = o1;
  *(uint4*)(dstp + 8) = o2;
}

// ---------------- fused gather100 + x1 (eighth-wave, 8-edge unroll)
// Brh cols 100-127 are unwritten garbage: accumulates into Ar cols 100-127
// which are never read (VAR2 reads cols<100 only) — no memset needed.
__global__ __launch_bounds__(256) void gather100e_x1(
    const u8* __restrict__ Brh, float* __restrict__ Ar,
    const int* __restrict__ ptr, const int2* __restrict__ csr, int M)
{
  const int node = (blockIdx.x * 256 + threadIdx.x) >> 3;
  const int sub  = threadIdx.x & 7;
  if (node >= M) return;
  const int beg = ptr[node], end = ptr[node + 1];
  float a[16] = {};
  int p = beg;
  for (; p + 8 <= end; p += 8) {
    int2 e[8];
#pragma unroll
    for (int q = 0; q < 8; ++q) e[q] = csr[p + q];
    uint4 v[8];
#pragma unroll
    for (int q = 0; q < 8; ++q)
      v[q] = *(const uint4*)(Brh + (size_t)e[q].x * 128 + sub * 16);
#pragma unroll
    for (int q = 0; q < 8; ++q) { const float wq = __int_as_float(e[q].y); ACCV(v[q], wq) }
  }
  for (; p < end; ++p) {
    const int2 eq = csr[p]; const float wq = __int_as_float(eq.y);
    const uint4 v = *(const uint4*)(Brh + (size_t)eq.x * 128 + sub * 16);
    ACCV(v, wq)
  }
  float* dstp = Ar + (size_t)node * 128 + sub * 16;
#pragma unroll
  for (int q = 0; q < 4; ++q) {
    float4 b = *(const float4*)(dstp + q * 4);
    b.x = fmaxf(b.x + a[q * 4 + 0], 0.f);
    b.y = fmaxf(b.y + a[q * 4 + 1], 0.f);
    b.z = fmaxf(b.z + a[q * 4 + 2], 0.f);
    b.w = fmaxf(b.w + a[q * 4 + 3], 0.f);
    *(float4*)(dstp + q * 4) = b;
  }
}
#undef ACCV

// ---------------- loss: eighth-wave per pair, 4-way pair ILP.
// zf8 cols 100-127 unwritten garbage: mask bytes >=100 on BOTH operands
// (sub 6 keeps only .x = bytes 96-99; sub 7 contributes nothing).
__device__ __forceinline__ void maskrow(uint4& r, int sub) {
  if (sub >= 6) { r.y = 0u; r.z = 0u; r.w = 0u; if (sub == 7) r.x = 0u; }
}
#define DOTV(uu, vv, s) { f32x2 p_, q_; \
  p_ = cvt2lo(uu.x); q_ = cvt2lo(vv.x); s = fmaf(p_.x, q_.x, s); s = fmaf(p_.y, q_.y, s); \
  p_ = cvt2hi(uu.x); q_ = cvt2hi(vv.x); s = fmaf(p_.x, q_.x, s); s = fmaf(p_.y, q_.y, s); \
  p_ = cvt2lo(uu.y); q_ = cvt2lo(vv.y); s = fmaf(p_.x, q_.x, s); s = fmaf(p_.y, q_.y, s); \
  p_ = cvt2hi(uu.y); q_ = cvt2hi(vv.y); s = fmaf(p_.x, q_.x, s); s = fmaf(p_.y, q_.y, s); \
  p_ = cvt2lo(uu.z); q_ = cvt2lo(vv.z); s = fmaf(p_.x, q_.x, s); s = fmaf(p_.y, q_.y, s); \
  p_ = cvt2hi(uu.z); q_ = cvt2hi(vv.z); s = fmaf(p_.x, q_.x, s); s = fmaf(p_.y, q_.y, s); \
  p_ = cvt2lo(uu.w); q_ = cvt2lo(vv.w); s = fmaf(p_.x, q_.x, s); s = fmaf(p_.y, q_.y, s); \
  p_ = cvt2hi(uu.w); q_ = cvt2hi(vv.w); s = fmaf(p_.x, q_.x, s); s = fmaf(p_.y, q_.y, s); }

__global__ __launch_bounds__(256) void loss_fp8(
    const u8* __restrict__ zf8, const int* __restrict__ ep,
    const int* __restrict__ en, int P, float* __restrict__ acc)
{
  __shared__ float red[8];
  const int tid = threadIdx.x;
  const int lane = tid & 63, wib = tid >> 6;
  const int sub = tid & 7;
  const int slot0 = blockIdx.x * 32 + (tid >> 3);
  const int step = gridDim.x * 32;
  float tp = 0.f, tn = 0.f;
  int g = slot0;
  for (; g + 3 * step < 2 * P; g += 4 * step) {
    int neg[4], na[4], nb[4];
#pragma unroll
    for (int q = 0; q < 4; ++q) {
      const int gq = g + q * step;
      neg[q] = (gq >= P);
      const int p = neg[q] ? gq - P : gq;
      const int* ia = neg[q] ? en : ep;
      na[q] = ia[p]; nb[q] = ia[P + p];
    }
    uint4 ra[4], rb[4];
#pragma unroll
    for (int q = 0; q < 4; ++q) {
      ra[q] = *(const uint4*)(zf8 + (size_t)na[q] * 128 + sub * 16);
      rb[q] = *(const uint4*)(zf8 + (size_t)nb[q] * 128 + sub * 16);
      maskrow(ra[q], sub); maskrow(rb[q], sub);
    }
    float s[4] = {0.f, 0.f, 0.f, 0.f};
#pragma unroll
    for (int q = 0; q < 4; ++q) DOTV(ra[q], rb[q], s[q])
#pragma unroll
    for (int off = 4; off; off >>= 1) {
#pragma unroll
      for (int q = 0; q < 4; ++q) s[q] += __shfl_down(s[q], off, 8);
    }
    if (sub == 0) {
#pragma unroll
      for (int q = 0; q < 4; ++q) {
        const float sig = 1.f / (1.f + expf(-s[q]));
        if (neg[q]) tn += logf(1.f - sig + 1e-15f); else tp += logf(sig + 1e-15f);
      }
    }
  }
  for (; g < 2 * P; g += step) {
    const int neg = (g >= P);
    const int p = neg ? g - P : g;
    const int* ia = neg ? en : ep;
    const int na = ia[p], nb = ia[P + p];
    uint4 ra = *(const uint4*)(zf8 + (size_t)na * 128 + sub * 16);
    uint4 rb = *(const uint4*)(zf8 + (size_t)nb * 128 + sub * 16);
    maskrow(ra, sub); maskrow(rb, sub);
    float s = 0.f;
    DOTV(ra, rb, s)
#pragma unroll
    for (int off = 4; off; off >>= 1) s += __shfl_down(s, off, 8);
    if (sub == 0) {
      const float sig = 1.f / (1.f + expf(-s));
      if (neg) tn += logf(1.f - sig + 1e-15f); else tp += logf(sig + 1e-15f);
    }
  }
  tp += __shfl_down(tp, 32, 64); tn += __shfl_down(tn, 32, 64);
  tp += __shfl_down(tp, 16, 64); tn += __shfl_down(tn, 16, 64);
  tp += __shfl_down(tp, 8, 64);  tn += __shfl_down(tn, 8, 64);
  if (lane == 0) { red[wib] = tp; red[4 + wib] = tn; }
  __syncthreads();
  if (tid == 0) {
    atomicAdd(acc + 0, red[0] + red[1] + red[2] + red[3]);
    atomicAdd(acc + 1, red[4] + red[5] + red[6] + red[7]);
  }
}
#undef DOTV

// ---------------- fused gather2 + final (int2 CSR)
__global__ void gather2_final(
    const float* __restrict__ t1, const float* __restrict__ t0,
    const int* __restrict__ ptr, const int2* __restrict__ csr,
    const float* __restrict__ accs,
    const float* __restrict__ c1, const float* __restrict__ c2,
    float* __restrict__ out, int M, float invP)
{
  const int i = blockIdx.x * blockDim.x + threadIdx.x;
  if (i < M) {
    float a0 = 0.f, a1 = 0.f;
    const int beg = ptr[i], end = ptr[i + 1];
    int p = beg;
    for (; p + 4 <= end; p += 4) {
      const int2 e0 = csr[p], e1 = csr[p + 1], e2 = csr[p + 2], e3 = csr[p + 3];
      const float w0 = __int_as_float(e0.y), w1 = __int_as_float(e1.y);
      const float w2 = __int_as_float(e2.y), w3 = __int_as_float(e3.y);
      const float2 v0 = *(const float2*)(t1 + (size_t)e0.x * 2);
      const float2 v1 = *(const float2*)(t1 + (size_t)e1.x * 2);
      const float2 v2 = *(const float2*)(t1 + (size_t)e2.x * 2);
      const float2 v3 = *(const float2*)(t1 + (size_t)e3.x * 2);
      a0 = fmaf(w0, v0.x, a0); a1 = fmaf(w0, v0.y, a1);
      a0 = fmaf(w1, v1.x, a0); a1 = fmaf(w1, v1.y, a1);
      a0 = fmaf(w2, v2.x, a0); a1 = fmaf(w2, v2.y, a1);
      a0 = fmaf(w3, v3.x, a0); a1 = fmaf(w3, v3.y, a1);
    }
    for (; p < end; ++p) {
      const int2 eq = csr[p]; const float wq = __int_as_float(eq.y);
      const float2 v = *(const float2*)(t1 + (size_t)eq.x * 2);
      a0 = fmaf(wq, v.x, a0); a1 = fmaf(wq, v.y, a1);
    }
    const float2 base = *(const float2*)(t0 + (size_t)i * 2);
    *(float2*)(out + (size_t)i * 2) = make_float2(base.x + a0, base.y + a1);
  }
  if (i == 0) {
    out[2 * M + 0] = -(accs[0] + accs[1]) * invP;
    out[2 * M + 1] = c1[0];
    out[2 * M + 2] = c2[0];
  }
}

extern "C" void kernel_launch(void* const* d_in, const int* in_sizes, int n_in,
                              void* d_out, int out_size, void* d_ws, size_t ws_size,
                              hipStream_t stream)
{
  const float* x   = (const float*)d_in[0];
  const int*   ei  = (const int*)d_in[1];
  const int*   ep  = (const int*)d_in[2];
  const int*   en  = (const int*)d_in[3];
  const float* W1  = (const float*)d_in[4];
  const float* b1  = (const float*)d_in[5];
  const float* W2  = (const float*)d_in[6];
  const float* b2  = (const float*)d_in[7];
  const float* W3  = (const float*)d_in[8];
  const float* b3  = (const float*)d_in[9];
  const float* l1W = (const float*)d_in[10];
  const float* l1b = (const float*)d_in[11];
  const float* l2W = (const float*)d_in[12];
  const float* l2b = (const float*)d_in[13];
  const float* c1  = (const float*)d_in[14];
  const float* c2  = (const float*)d_in[15];
  float* out = (float*)d_out;

  const int M = in_sizes[0] / 128;  // 50000
  const int E = in_sizes[1] / 2;    // 800000
  const int P = in_sizes[2] / 2;    // 400000
  const int* src = ei;
  const int* dst = ei + E;
  const int nb_scan = (M + 255) / 256;

  float* ws = (float*)d_ws;
  size_t o = 0;
  float*    dinv = ws + o;            o += 50176;
  int*      cnt  = (int*)(ws + o);    o += (size_t)M;
  int*      ptr  = (int*)(ws + o);    o += (size_t)M + 8;
  int*      bsum = (int*)(ws + o);    o += 256;
  int2*     csr  = (int2*)(ws + o);   o += (size_t)E * 2;      // packed {src, wbits}
  ushort_t* rank = (ushort_t*)(ws + o); o += (size_t)E / 2;
  ushort_t* xb   = (ushort_t*)(ws + o); o += (size_t)M * 64;   // bf16 [M][128]
  u8*       xf8  = (u8*)(ws + o);     o += (size_t)M * 32;     // fp8 [M][128]
  ushort_t* tx0b = (ushort_t*)(ws + o); o += (size_t)M * 64;   // bf16 [M][128]
  ushort_t* W1t  = (ushort_t*)(ws + o); o += 40960;            // [320][256]
  ushort_t* W2t  = (ushort_t*)(ws + o); o += 35840;            // [224][320]
  ushort_t* Wlt  = (ushort_t*)(ws + o); o += 14336;            // [224][128]
  ushort_t* h    = (ushort_t*)(ws + o); o += (size_t)M * 160;  // bf16 [M][320], 32MB
  float*    Ar   = ws + o;            o += (size_t)M * 128;    // f32 stride128, 25.6MB
  u8*       Brh  = (u8*)(ws + o);     o += (size_t)M * 32;     // fp8 [M][128]
  u8*       zf8  = (u8*)(ws + o);     o += (size_t)M * 32;     // fp8 [M][128]
  float*    t0   = ws + o;            o += (size_t)M * 2;
  float*    t1   = ws + o;            o += (size_t)M * 2;
  float*    accs = ws + o;            o += 8;
  // partial tables alias regions dead during CSR build:
  unsigned* partS = (unsigned*)h;   // 25.6MB <= 32MB (h written after fill)
  unsigned* partD = (unsigned*)Ar;  // 25.6MB == Ar size (written after fill)

  // packing + conversion (independent, early); no memsets needed (R9)
  const int n4 = M * 32;
  pack_cvt<<<(n4 + 182272 + 255) / 256, 256, 0, stream>>>(
      x, xb, xf8, n4, W1, W2, l1W, l2W, W1t, W2t, Wlt);

  // CSR build (no global atomics)
  hist2<<<NB_H, 256, 0, stream>>>(src, dst, E, M, partS, partD, rank);
  reduce_base2<<<(2 * PW + 255) / 256, 256, 0, stream>>>(partS, partD, dinv, cnt, M);
  scan_local<<<nb_scan, 256, 0, stream>>>(cnt, ptr, bsum, M);
  scan_bsum<<<1, 256, 0, stream>>>(bsum, nb_scan, accs);
  scan_add<<<nb_scan, 256, 0, stream>>>(ptr, bsum, M, E);
  fill_csr2<<<(E + 255) / 256, 256, 0, stream>>>(src, dst, dinv, ptr, partD, rank, csr, E);

  const int gB = (M + 63) / 64;
  const int gE8 = (M * 8 + 255) / 256;

  // conv1
  gather128e<<<gE8, 256, 0, stream>>>(xf8, tx0b, ptr, csr, M);
  gemm_mfma<0, 320, 256><<<gB, 256, 0, stream>>>(
      xb, tx0b, W1t, b1, nullptr, nullptr, nullptr, nullptr, h, nullptr, nullptr, nullptr, M);

  // conv2 (propagate after GEMM at 100)
  gemm_mfma<1, 224, 320><<<gB, 256, 0, stream>>>(
      h, nullptr, W2t, b2, nullptr, nullptr, nullptr, nullptr, Ar, Brh, nullptr, nullptr, M);
  gather100e_x1<<<gE8, 256, 0, stream>>>(Brh, Ar, ptr, csr, M);

  // lins + fused w3 (x2 never materialized)
  gemm_mfma<2, 224, 128><<<gB, 256, 0, stream>>>(
      xb, nullptr, Wlt, l1b, l2b, Ar /*x1*/, W3, b3, nullptr, zf8, t0, t1, M);

  // loss
  loss_fp8<<<2048, 256, 0, stream>>>(zf8, ep, en, P, accs);

  // conv3 propagation + final
  gather2_final<<<(M + 255) / 256, 256, 0, stream>>>(t1, t0, ptr, csr,
                                                     accs, c1, c2, out, M, 1.0f / (float)P);
}